// Round 1
// baseline (858.579 us; speedup 1.0000x reference)
//
#include <hip/hip_runtime.h>
#include <hip/hip_bf16.h>

#define NT 4096          // B*T tokens
#define HD 2048          // hidden
#define NE 8             // experts
#define TOPK 2
#define ID 1408          // intermediate
#define NG 9             // 8 experts + shared
#define NPAIR (NT*TOPK + NT)   // 12288 rows total
#define BM 64
#define BN 64
#define BK 64
#define MT_MAX 200       // >= worst-case sum of ceil(cnt/64) (135) + 64 shared

typedef unsigned short u16;
typedef unsigned int u32;
typedef __attribute__((ext_vector_type(8))) short bf16x8;
typedef __attribute__((ext_vector_type(4))) float f32x4;

__device__ __forceinline__ u16 f2bf(float f) {
    u32 u = __builtin_bit_cast(u32, f);
    u += 0x7FFFu + ((u >> 16) & 1u);   // round-to-nearest-even
    return (u16)(u >> 16);
}

struct Bits16 { uint2 a, b; };
__device__ __forceinline__ bf16x8 load_frag(const u16* p) {
    Bits16 s;
    s.a = *(const uint2*)(p);        // k-half 0: 4 bf16
    s.b = *(const uint2*)(p + 16);   // k-half 1 (k+16): 4 bf16
    return __builtin_bit_cast(bf16x8, s);
}

// ---------------- router: logits -> softmax -> top2 + importance/counts ----
__global__ void router_kernel(const float* __restrict__ x, const float* __restrict__ gw,
                              int* __restrict__ counts, float* __restrict__ imp,
                              int* __restrict__ tki, float* __restrict__ tkv) {
    __shared__ float s_imp[NE];
    __shared__ int s_cnt[NE];
    if (threadIdx.x < NE) { s_imp[threadIdx.x] = 0.f; s_cnt[threadIdx.x] = 0; }
    int w = threadIdx.x >> 6, lane = threadIdx.x & 63;
    int t = blockIdx.x * 4 + w;
    float acc[NE];
#pragma unroll
    for (int e = 0; e < NE; e++) acc[e] = 0.f;
    const float* xr = x + (size_t)t * HD;
    for (int i = 0; i < HD / 64; i++) {
        float xv = xr[lane + 64 * i];
#pragma unroll
        for (int e = 0; e < NE; e++) acc[e] += xv * gw[e * HD + lane + 64 * i];
    }
#pragma unroll
    for (int e = 0; e < NE; e++) {
#pragma unroll
        for (int o = 32; o >= 1; o >>= 1) acc[e] += __shfl_xor(acc[e], o, 64);
    }
    __syncthreads();  // s_imp/s_cnt init done
    if (lane == 0) {
        float mx = acc[0];
        for (int e = 1; e < NE; e++) mx = fmaxf(mx, acc[e]);
        float p[NE], sum = 0.f;
        for (int e = 0; e < NE; e++) { p[e] = expf(acc[e] - mx); sum += p[e]; }
        float inv = 1.f / sum;
        for (int e = 0; e < NE; e++) p[e] *= inv;
        // top-2 on probs, ties -> lower index (matches jax.lax.top_k)
        int i1 = 0;
        for (int e = 1; e < NE; e++) if (p[e] > p[i1]) i1 = e;
        int i2 = (i1 == 0) ? 1 : 0;
        for (int e = 0; e < NE; e++) if (e != i1 && p[e] > p[i2]) i2 = e;
        tki[t * 2 + 0] = i1; tkv[t * 2 + 0] = p[i1];
        tki[t * 2 + 1] = i2; tkv[t * 2 + 1] = p[i2];
        for (int e = 0; e < NE; e++) atomicAdd(&s_imp[e], p[e]);
        atomicAdd(&s_cnt[i1], 1); atomicAdd(&s_cnt[i2], 1);
    }
    __syncthreads();
    if (threadIdx.x < NE) {
        atomicAdd(&imp[threadIdx.x], s_imp[threadIdx.x]);
        atomicAdd(&counts[threadIdx.x], s_cnt[threadIdx.x]);
    }
}

// ---------------- prep: offsets, tile offsets, aux loss ---------------------
__global__ void prep_kernel(const int* __restrict__ counts, const float* __restrict__ imp,
                            int* __restrict__ off, int* __restrict__ tileoff,
                            float* __restrict__ out_aux) {
    if (threadIdx.x == 0 && blockIdx.x == 0) {
        int o = 0, to = 0;
        for (int g = 0; g < NG; g++) {
            int c = (g < NE) ? counts[g] : NT;
            off[g] = o; tileoff[g] = to;
            o += c; to += (c + BM - 1) / BM;
        }
        off[NG] = o; tileoff[NG] = to;
        float aux = 0.f;
        for (int e = 0; e < NE; e++)
            aux += (imp[e] / (float)NT) * ((float)counts[e] / (float)(NT * TOPK));
        *out_aux = aux * (float)NE;
    }
}

// ---------------- scatter: build per-group token lists ----------------------
__global__ void scatter_kernel(const int* __restrict__ tki, const float* __restrict__ tkv,
                               const int* __restrict__ off, int* __restrict__ cursor,
                               int* __restrict__ list, float* __restrict__ wgt) {
    int t = blockIdx.x * blockDim.x + threadIdx.x;
    if (t >= NT) return;
#pragma unroll
    for (int k = 0; k < TOPK; k++) {
        int e = tki[t * 2 + k];
        int pos = atomicAdd(&cursor[e], 1);
        list[off[e] + pos] = t;
        wgt[off[e] + pos] = tkv[t * 2 + k];
    }
    list[off[NE] + t] = t;   // shared-expert group: identity
    wgt[off[NE] + t] = 1.0f;
}

// ---------------- fc1: h1 = SiLU(x_gathered @ W1_g), bf16 out ---------------
__global__ __launch_bounds__(256) void fc1_kernel(
    const float* __restrict__ x, const float* __restrict__ W1, const float* __restrict__ Ws1,
    const int* __restrict__ off, const int* __restrict__ tileoff,
    const int* __restrict__ list, u16* __restrict__ h1) {
    __shared__ u16 As[BM][BK + 8];
    __shared__ u16 Bs[BN][BK + 8];
    int mt = blockIdx.y;
    int g = -1, gto = 0;
#pragma unroll
    for (int gg = 0; gg < NG; gg++)
        if (mt >= tileoff[gg] && mt < tileoff[gg + 1]) { g = gg; gto = tileoff[gg]; }
    if (g < 0) return;
    int goff = off[g];
    int cnt = off[g + 1] - goff;
    int row0 = (mt - gto) * BM;
    const float* Wb = (g < NE) ? (W1 + (size_t)g * HD * ID) : Ws1;
    int n0 = blockIdx.x * BN;

    int th = threadIdx.x;
    int ar = th >> 2, aq = th & 3;          // A staging: row, 16-col quarter
    const float* xrow = nullptr;
    if (row0 + ar < cnt) xrow = x + (size_t)list[goff + row0 + ar] * HD;
    int bkr = th >> 4, bnc = (th & 15) * 4; // B staging

    int lane = th & 63;
    int wr = (th >> 7) & 1, wc = (th >> 6) & 1;
    int lrow = lane & 15, lg4 = (lane >> 4) * 4;

    f32x4 acc[2][2] = {};
    for (int k0 = 0; k0 < HD; k0 += BK) {
        if (xrow) {
            const float* s = xrow + k0 + aq * 16;
            u16* d = &As[ar][aq * 16];
#pragma unroll
            for (int j = 0; j < 4; j++) {
                float4 v = *(const float4*)(s + j * 4);
                ushort4 o;
                o.x = f2bf(v.x); o.y = f2bf(v.y); o.z = f2bf(v.z); o.w = f2bf(v.w);
                *(ushort4*)(d + j * 4) = o;
            }
        }
#pragma unroll
        for (int pp = 0; pp < 4; pp++) {
            int kr = bkr + pp * 16;
            float4 v = *(const float4*)(Wb + (size_t)(k0 + kr) * ID + n0 + bnc);
            Bs[bnc + 0][kr] = f2bf(v.x);
            Bs[bnc + 1][kr] = f2bf(v.y);
            Bs[bnc + 2][kr] = f2bf(v.z);
            Bs[bnc + 3][kr] = f2bf(v.w);
        }
        __syncthreads();
#pragma unroll
        for (int kk = 0; kk < BK; kk += 32) {
            bf16x8 a0 = load_frag(&As[wr * 32 + 0 + lrow][kk + lg4]);
            bf16x8 a1 = load_frag(&As[wr * 32 + 16 + lrow][kk + lg4]);
            bf16x8 b0 = load_frag(&Bs[wc * 32 + 0 + lrow][kk + lg4]);
            bf16x8 b1 = load_frag(&Bs[wc * 32 + 16 + lrow][kk + lg4]);
            acc[0][0] = __builtin_amdgcn_mfma_f32_16x16x32_bf16(a0, b0, acc[0][0], 0, 0, 0);
            acc[0][1] = __builtin_amdgcn_mfma_f32_16x16x32_bf16(a0, b1, acc[0][1], 0, 0, 0);
            acc[1][0] = __builtin_amdgcn_mfma_f32_16x16x32_bf16(a1, b0, acc[1][0], 0, 0, 0);
            acc[1][1] = __builtin_amdgcn_mfma_f32_16x16x32_bf16(a1, b1, acc[1][1], 0, 0, 0);
        }
        __syncthreads();
    }
#pragma unroll
    for (int mf = 0; mf < 2; mf++) {
#pragma unroll
        for (int reg = 0; reg < 4; reg++) {
            int ml = row0 + wr * 32 + mf * 16 + lg4 + reg;
            if (ml < cnt) {
                size_t rb = (size_t)(goff + ml) * ID + n0 + wc * 32;
#pragma unroll
                for (int nf = 0; nf < 2; nf++) {
                    float v = acc[mf][nf][reg];
                    float s = v / (1.f + expf(-v));   // SiLU
                    h1[rb + nf * 16 + lrow] = f2bf(s);
                }
            }
        }
    }
}

// ---------------- fc2: y[token] += wgt * (h1 @ W2_g) ------------------------
__global__ __launch_bounds__(256) void fc2_kernel(
    const u16* __restrict__ h1, const float* __restrict__ W2, const float* __restrict__ Ws2,
    const int* __restrict__ off, const int* __restrict__ tileoff,
    const int* __restrict__ list, const float* __restrict__ wgt, float* __restrict__ y) {
    __shared__ u16 As[BM][BK + 8];
    __shared__ u16 Bs[BN][BK + 8];
    int mt = blockIdx.y;
    int g = -1, gto = 0;
#pragma unroll
    for (int gg = 0; gg < NG; gg++)
        if (mt >= tileoff[gg] && mt < tileoff[gg + 1]) { g = gg; gto = tileoff[gg]; }
    if (g < 0) return;
    int goff = off[g];
    int cnt = off[g + 1] - goff;
    int row0 = (mt - gto) * BM;
    const float* Wb = (g < NE) ? (W2 + (size_t)g * ID * HD) : Ws2;
    int n0 = blockIdx.x * BN;

    int th = threadIdx.x;
    int ar = th >> 2, aq = th & 3;
    const u16* arow = nullptr;
    if (row0 + ar < cnt) arow = h1 + (size_t)(goff + row0 + ar) * ID;
    int bkr = th >> 4, bnc = (th & 15) * 4;

    int lane = th & 63;
    int wr = (th >> 7) & 1, wc = (th >> 6) & 1;
    int lrow = lane & 15, lg4 = (lane >> 4) * 4;

    f32x4 acc[2][2] = {};
    for (int k0 = 0; k0 < ID; k0 += BK) {   // 22 iters, exact
        if (arow) {
            const u16* s = arow + k0 + aq * 16;
            *(uint4*)&As[ar][aq * 16 + 0] = *(const uint4*)(s + 0);
            *(uint4*)&As[ar][aq * 16 + 8] = *(const uint4*)(s + 8);
        }
#pragma unroll
        for (int pp = 0; pp < 4; pp++) {
            int kr = bkr + pp * 16;
            float4 v = *(const float4*)(Wb + (size_t)(k0 + kr) * HD + n0 + bnc);
            Bs[bnc + 0][kr] = f2bf(v.x);
            Bs[bnc + 1][kr] = f2bf(v.y);
            Bs[bnc + 2][kr] = f2bf(v.z);
            Bs[bnc + 3][kr] = f2bf(v.w);
        }
        __syncthreads();
#pragma unroll
        for (int kk = 0; kk < BK; kk += 32) {
            bf16x8 a0 = load_frag(&As[wr * 32 + 0 + lrow][kk + lg4]);
            bf16x8 a1 = load_frag(&As[wr * 32 + 16 + lrow][kk + lg4]);
            bf16x8 b0 = load_frag(&Bs[wc * 32 + 0 + lrow][kk + lg4]);
            bf16x8 b1 = load_frag(&Bs[wc * 32 + 16 + lrow][kk + lg4]);
            acc[0][0] = __builtin_amdgcn_mfma_f32_16x16x32_bf16(a0, b0, acc[0][0], 0, 0, 0);
            acc[0][1] = __builtin_amdgcn_mfma_f32_16x16x32_bf16(a0, b1, acc[0][1], 0, 0, 0);
            acc[1][0] = __builtin_amdgcn_mfma_f32_16x16x32_bf16(a1, b0, acc[1][0], 0, 0, 0);
            acc[1][1] = __builtin_amdgcn_mfma_f32_16x16x32_bf16(a1, b1, acc[1][1], 0, 0, 0);
        }
        __syncthreads();
    }
#pragma unroll
    for (int mf = 0; mf < 2; mf++) {
#pragma unroll
        for (int reg = 0; reg < 4; reg++) {
            int ml = row0 + wr * 32 + mf * 16 + lg4 + reg;
            if (ml < cnt) {
                int slot = goff + ml;
                int tok = list[slot];
                float wv = wgt[slot];
                float* yr = y + (size_t)tok * HD + n0 + wc * 32;
#pragma unroll
                for (int nf = 0; nf < 2; nf++)
                    atomicAdd(yr + nf * 16 + lrow, acc[mf][nf][reg] * wv);
            }
        }
    }
}

// ---------------- launch -----------------------------------------------------
extern "C" void kernel_launch(void* const* d_in, const int* in_sizes, int n_in,
                              void* d_out, int out_size, void* d_ws, size_t ws_size,
                              hipStream_t stream) {
    const float* x   = (const float*)d_in[0];
    const float* gw  = (const float*)d_in[1];
    const float* W1  = (const float*)d_in[2];
    const float* W2  = (const float*)d_in[3];
    const float* Ws1 = (const float*)d_in[4];
    const float* Ws2 = (const float*)d_in[5];
    float* out = (float*)d_out;

    char* ws = (char*)d_ws;
    int*   counts  = (int*)(ws + 0);
    int*   cursor  = (int*)(ws + 64);
    int*   off     = (int*)(ws + 128);
    int*   tileoff = (int*)(ws + 192);
    float* imp     = (float*)(ws + 256);
    int*   tki     = (int*)(ws + 320);
    float* tkv     = (float*)(ws + 320 + NT * TOPK * 4);
    int*   list    = (int*)(ws + 320 + NT * TOPK * 8);
    float* wgt     = (float*)(ws + 320 + NT * TOPK * 8 + NPAIR * 4);
    u16*   h1      = (u16*)(ws + 164352);

    hipMemsetAsync(d_out, 0, (size_t)out_size * sizeof(float), stream);
    hipMemsetAsync(d_ws, 0, 320, stream);

    router_kernel<<<NT / 4, 256, 0, stream>>>(x, gw, counts, imp, tki, tkv);
    prep_kernel<<<1, 64, 0, stream>>>(counts, imp, off, tileoff, out + (size_t)NT * HD);
    scatter_kernel<<<NT / 256, 256, 0, stream>>>(tki, tkv, off, cursor, list, wgt);
    fc1_kernel<<<dim3(ID / BN, MT_MAX), 256, 0, stream>>>(x, W1, Ws1, off, tileoff, list, h1);
    fc2_kernel<<<dim3(HD / BN, MT_MAX), 256, 0, stream>>>(h1, W2, Ws2, off, tileoff, list, wgt, out);
}

// Round 2
// 664.268 us; speedup vs baseline: 1.2925x; 1.2925x over previous
//
#include <hip/hip_runtime.h>
#include <hip/hip_bf16.h>

#define NT 4096          // B*T tokens
#define HD 2048          // hidden
#define NE 8             // experts
#define TOPK 2
#define ID 1408          // intermediate
#define NG 9             // 8 experts + shared
#define NPAIR (NT*TOPK + NT)   // 12288 rows total
#define BM 128
#define BN 128
#define BK 64
#define MT_MAX 104       // max sum of ceil(cnt/128) over groups: 72 + 32

typedef unsigned short u16;
typedef unsigned int u32;
typedef unsigned long long u64;
typedef __attribute__((ext_vector_type(8))) short bf16x8;
typedef __attribute__((ext_vector_type(4))) float f32x4;

__device__ __forceinline__ u16 f2bf(float f) {
    u32 u = __builtin_bit_cast(u32, f);
    u += 0x7FFFu + ((u >> 16) & 1u);   // round-to-nearest-even
    return (u16)(u >> 16);
}

// async global->LDS, 16B per lane; lds base must be wave-uniform
typedef __attribute__((address_space(1))) const void gas_void;
typedef __attribute__((address_space(3))) void las_void;
__device__ __forceinline__ void gl_lds16(const void* g, void* l) {
    __builtin_amdgcn_global_load_lds((gas_void*)(u64)g, (las_void*)(u32)(u64)l, 16, 0, 0);
}

// unpermuted A-frag load (two k-halves 16 elems apart)
struct Bits16 { uint2 a, b; };
__device__ __forceinline__ bf16x8 load_frag(const u16* p) {
    Bits16 s;
    s.a = *(const uint2*)(p);
    s.b = *(const uint2*)(p + 16);
    return __builtin_bit_cast(bf16x8, s);
}

// ---------------- router: logits -> softmax -> top2 + importance/counts ----
__global__ void router_kernel(const float* __restrict__ x, const float* __restrict__ gw,
                              int* __restrict__ counts, float* __restrict__ imp,
                              int* __restrict__ tki, float* __restrict__ tkv) {
    __shared__ float s_imp[NE];
    __shared__ int s_cnt[NE];
    if (threadIdx.x < NE) { s_imp[threadIdx.x] = 0.f; s_cnt[threadIdx.x] = 0; }
    int w = threadIdx.x >> 6, lane = threadIdx.x & 63;
    int t = blockIdx.x * 4 + w;
    float acc[NE];
#pragma unroll
    for (int e = 0; e < NE; e++) acc[e] = 0.f;
    const float* xr = x + (size_t)t * HD;
    for (int i = 0; i < HD / 64; i++) {
        float xv = xr[lane + 64 * i];
#pragma unroll
        for (int e = 0; e < NE; e++) acc[e] += xv * gw[e * HD + lane + 64 * i];
    }
#pragma unroll
    for (int e = 0; e < NE; e++) {
#pragma unroll
        for (int o = 32; o >= 1; o >>= 1) acc[e] += __shfl_xor(acc[e], o, 64);
    }
    __syncthreads();
    if (lane == 0) {
        float mx = acc[0];
        for (int e = 1; e < NE; e++) mx = fmaxf(mx, acc[e]);
        float p[NE], sum = 0.f;
        for (int e = 0; e < NE; e++) { p[e] = expf(acc[e] - mx); sum += p[e]; }
        float inv = 1.f / sum;
        for (int e = 0; e < NE; e++) p[e] *= inv;
        int i1 = 0;
        for (int e = 1; e < NE; e++) if (p[e] > p[i1]) i1 = e;
        int i2 = (i1 == 0) ? 1 : 0;
        for (int e = 0; e < NE; e++) if (e != i1 && p[e] > p[i2]) i2 = e;
        tki[t * 2 + 0] = i1; tkv[t * 2 + 0] = p[i1];
        tki[t * 2 + 1] = i2; tkv[t * 2 + 1] = p[i2];
        for (int e = 0; e < NE; e++) atomicAdd(&s_imp[e], p[e]);
        atomicAdd(&s_cnt[i1], 1); atomicAdd(&s_cnt[i2], 1);
    }
    __syncthreads();
    if (threadIdx.x < NE) {
        atomicAdd(&imp[threadIdx.x], s_imp[threadIdx.x]);
        atomicAdd(&counts[threadIdx.x], s_cnt[threadIdx.x]);
    }
}

// ---------------- prep: offsets, tile offsets (BM=128), aux loss ------------
__global__ void prep_kernel(const int* __restrict__ counts, const float* __restrict__ imp,
                            int* __restrict__ off, int* __restrict__ tileoff,
                            float* __restrict__ out_aux) {
    if (threadIdx.x == 0 && blockIdx.x == 0) {
        int o = 0, to = 0;
        for (int g = 0; g < NG; g++) {
            int c = (g < NE) ? counts[g] : NT;
            off[g] = o; tileoff[g] = to;
            o += c; to += (c + BM - 1) / BM;
        }
        off[NG] = o; tileoff[NG] = to;
        float aux = 0.f;
        for (int e = 0; e < NE; e++)
            aux += (imp[e] / (float)NT) * ((float)counts[e] / (float)(NT * TOPK));
        *out_aux = aux * (float)NE;
    }
}

// ---------------- scatter: build per-group token lists ----------------------
__global__ void scatter_kernel(const int* __restrict__ tki, const float* __restrict__ tkv,
                               const int* __restrict__ off, int* __restrict__ cursor,
                               int* __restrict__ list, float* __restrict__ wgt) {
    int t = blockIdx.x * blockDim.x + threadIdx.x;
    if (t >= NT) return;
#pragma unroll
    for (int k = 0; k < TOPK; k++) {
        int e = tki[t * 2 + k];
        int pos = atomicAdd(&cursor[e], 1);
        list[off[e] + pos] = t;
        wgt[off[e] + pos] = tkv[t * 2 + k];
    }
    list[off[NE] + t] = t;
    wgt[off[NE] + t] = 1.0f;
}

// ---------------- convert x -> bf16 with k-frag perm within 64-blocks -------
// perm: k = h*32+s*16+q*4+r  ->  c = h*32+q*8+s*4+r
__global__ void convx_kernel(const float* __restrict__ x, u16* __restrict__ xb) {
    int c = blockIdx.x * 256 + threadIdx.x;       // chunk of 8 bf16
    int t = c >> 8;                                // 256 chunks per token
    int cc = c & 255;
    int b64 = cc >> 3, j = cc & 7;
    int h = j >> 2, q = j & 3;
    size_t base = (size_t)t * HD + b64 * 64 + h * 32 + q * 4;
    float4 v0 = *(const float4*)(x + base);
    float4 v1 = *(const float4*)(x + base + 16);
    ushort4 o0, o1;
    o0.x = f2bf(v0.x); o0.y = f2bf(v0.y); o0.z = f2bf(v0.z); o0.w = f2bf(v0.w);
    o1.x = f2bf(v1.x); o1.y = f2bf(v1.y); o1.z = f2bf(v1.z); o1.w = f2bf(v1.w);
    uint4 o;
    o.x = (u32)o0.x | ((u32)o0.y << 16); o.y = (u32)o0.z | ((u32)o0.w << 16);
    o.z = (u32)o1.x | ((u32)o1.y << 16); o.w = (u32)o1.z | ((u32)o1.w << 16);
    *(uint4*)(xb + (size_t)t * HD + b64 * 64 + j * 8) = o;
}

// ---------------- transpose+convert weights: [K][N] f32 -> [N][K'] bf16 -----
__global__ void transw_kernel(const float* __restrict__ src, u16* __restrict__ dst,
                              int K, int N) {
    int e = blockIdx.z;
    src += (size_t)e * K * N;
    dst += (size_t)e * N * K;
    int k0 = blockIdx.y * 64, n0 = blockIdx.x * 64;
    __shared__ u16 Lt[64][68];    // [n][k], padded
    int tid = threadIdx.x;
#pragma unroll
    for (int i = 0; i < 4; i++) {
        int idx = i * 256 + tid;
        int kl = idx >> 4, nq = (idx & 15) * 4;
        float4 v = *(const float4*)(src + (size_t)(k0 + kl) * N + n0 + nq);
        Lt[nq + 0][kl] = f2bf(v.x); Lt[nq + 1][kl] = f2bf(v.y);
        Lt[nq + 2][kl] = f2bf(v.z); Lt[nq + 3][kl] = f2bf(v.w);
    }
    __syncthreads();
#pragma unroll
    for (int c2 = 0; c2 < 2; c2++) {
        int cid = tid * 2 + c2;
        int nr = cid >> 3, j = cid & 7;
        int h = j >> 2, q = j & 3;
        int kb = h * 32 + q * 4;
        uint2 lo = *(const uint2*)&Lt[nr][kb];
        uint2 hi = *(const uint2*)&Lt[nr][kb + 16];
        uint4 o; o.x = lo.x; o.y = lo.y; o.z = hi.x; o.w = hi.y;
        *(uint4*)(dst + (size_t)(n0 + nr) * K + k0 + j * 8) = o;
    }
}

// ---------------- fc1: h1 = SiLU(xb_gathered @ Wt1_g^T), bf16 out -----------
__global__ __launch_bounds__(256) void fc1_kernel(
    const u16* __restrict__ xb, const u16* __restrict__ Wt1,
    const int* __restrict__ off, const int* __restrict__ tileoff,
    const int* __restrict__ list, u16* __restrict__ h1) {
    __shared__ u16 As[BM * BK];
    __shared__ u16 Bs[BN * BK];
    int mt = blockIdx.y;
    int g = -1, gto = 0;
#pragma unroll
    for (int gg = 0; gg < NG; gg++)
        if (mt >= tileoff[gg] && mt < tileoff[gg + 1]) { g = gg; gto = tileoff[gg]; }
    if (g < 0) return;
    int goff = off[g], cnt = off[g + 1] - goff;
    int row0 = (mt - gto) * BM;
    const u16* Wb = Wt1 + (size_t)g * (ID * HD);
    int n0 = blockIdx.x * BN;
    int tid = threadIdx.x, lane = tid & 63, w = tid >> 6;
    int lm = lane >> 3, lc = (lane & 7) * 8;
    const u16* pa[4]; const u16* pb[4];
#pragma unroll
    for (int i = 0; i < 4; i++) {
        int c = i * 4 + w;
        int r = row0 + c * 8 + lm;
        r = (r < cnt) ? r : (cnt - 1);
        pa[i] = xb + (size_t)list[goff + r] * HD + lc;
        pb[i] = Wb + (size_t)(n0 + c * 8 + lm) * HD + lc;
    }
    int wr = w >> 1, wc = w & 1;
    int lr = lane & 15, q8 = (lane >> 4) * 8;
    f32x4 acc[4][4] = {};
    for (int k0 = 0; k0 < HD; k0 += BK) {
#pragma unroll
        for (int i = 0; i < 4; i++) {
            gl_lds16(pa[i], As + (i * 4 + w) * 512);
            gl_lds16(pb[i], Bs + (i * 4 + w) * 512);
            pa[i] += BK; pb[i] += BK;
        }
        __syncthreads();
#pragma unroll
        for (int kk = 0; kk < BK; kk += 32) {
            bf16x8 a[4], b[4];
#pragma unroll
            for (int f = 0; f < 4; f++) {
                a[f] = __builtin_bit_cast(bf16x8, *(const uint4*)&As[(wr * 64 + f * 16 + lr) * BK + kk + q8]);
                b[f] = __builtin_bit_cast(bf16x8, *(const uint4*)&Bs[(wc * 64 + f * 16 + lr) * BK + kk + q8]);
            }
#pragma unroll
            for (int mf = 0; mf < 4; mf++)
#pragma unroll
                for (int nf = 0; nf < 4; nf++)
                    acc[mf][nf] = __builtin_amdgcn_mfma_f32_16x16x32_bf16(a[mf], b[nf], acc[mf][nf], 0, 0, 0);
        }
        __syncthreads();
    }
    int q4 = (lane >> 4) * 4;
#pragma unroll
    for (int mf = 0; mf < 4; mf++)
#pragma unroll
        for (int reg = 0; reg < 4; reg++) {
            int r = row0 + wr * 64 + mf * 16 + q4 + reg;
            if (r < cnt) {
                size_t rb = (size_t)(goff + r) * ID + n0 + wc * 64;
#pragma unroll
                for (int nf = 0; nf < 4; nf++) {
                    float v = acc[mf][nf][reg];
                    h1[rb + nf * 16 + lr] = f2bf(v / (1.f + __expf(-v)));
                }
            }
        }
}

// ---------------- fc2: y[token] += wgt * (h1 @ Wt2_g^T) ---------------------
__global__ __launch_bounds__(256) void fc2_kernel(
    const u16* __restrict__ h1, const u16* __restrict__ Wt2,
    const int* __restrict__ off, const int* __restrict__ tileoff,
    const int* __restrict__ list, const float* __restrict__ wgt,
    float* __restrict__ y) {
    __shared__ u16 As[BM * BK];
    __shared__ u16 Bs[BN * BK];
    int mt = blockIdx.y;
    int g = -1, gto = 0;
#pragma unroll
    for (int gg = 0; gg < NG; gg++)
        if (mt >= tileoff[gg] && mt < tileoff[gg + 1]) { g = gg; gto = tileoff[gg]; }
    if (g < 0) return;
    int goff = off[g], cnt = off[g + 1] - goff;
    int row0 = (mt - gto) * BM;
    const u16* Wb = Wt2 + (size_t)g * (ID * HD);
    int n0 = blockIdx.x * BN;
    int tid = threadIdx.x, lane = tid & 63, w = tid >> 6;
    int lm = lane >> 3, lc = (lane & 7) * 8;
    const u16* pa[4]; const u16* pb[4];
#pragma unroll
    for (int i = 0; i < 4; i++) {
        int c = i * 4 + w;
        int r = row0 + c * 8 + lm;
        r = (r < cnt) ? r : (cnt - 1);
        pa[i] = h1 + (size_t)(goff + r) * ID + lc;           // slot-indexed, no perm
        pb[i] = Wb + (size_t)(n0 + c * 8 + lm) * ID + lc;    // perm'd weights
    }
    int wr = w >> 1, wc = w & 1;
    int lr = lane & 15, q8 = (lane >> 4) * 8, q4 = (lane >> 4) * 4;
    f32x4 acc[4][4] = {};
    for (int k0 = 0; k0 < ID; k0 += BK) {    // 22 iters exact
#pragma unroll
        for (int i = 0; i < 4; i++) {
            gl_lds16(pa[i], As + (i * 4 + w) * 512);
            gl_lds16(pb[i], Bs + (i * 4 + w) * 512);
            pa[i] += BK; pb[i] += BK;
        }
        __syncthreads();
#pragma unroll
        for (int kk = 0; kk < BK; kk += 32) {
            bf16x8 a[4], b[4];
#pragma unroll
            for (int f = 0; f < 4; f++) {
                a[f] = load_frag(&As[(wr * 64 + f * 16 + lr) * BK + kk + q4]);   // unperm'd
                b[f] = __builtin_bit_cast(bf16x8, *(const uint4*)&Bs[(wc * 64 + f * 16 + lr) * BK + kk + q8]);
            }
#pragma unroll
            for (int mf = 0; mf < 4; mf++)
#pragma unroll
                for (int nf = 0; nf < 4; nf++)
                    acc[mf][nf] = __builtin_amdgcn_mfma_f32_16x16x32_bf16(a[mf], b[nf], acc[mf][nf], 0, 0, 0);
        }
        __syncthreads();
    }
#pragma unroll
    for (int mf = 0; mf < 4; mf++)
#pragma unroll
        for (int reg = 0; reg < 4; reg++) {
            int r = row0 + wr * 64 + mf * 16 + q4 + reg;
            if (r < cnt) {
                int slot = goff + r;
                int tok = list[slot];
                float wv = wgt[slot];
                float* yr = y + (size_t)tok * HD + n0 + wc * 64;
#pragma unroll
                for (int nf = 0; nf < 4; nf++)
                    atomicAdd(yr + nf * 16 + lr, acc[mf][nf][reg] * wv);
            }
        }
}

// ---------------- launch -----------------------------------------------------
extern "C" void kernel_launch(void* const* d_in, const int* in_sizes, int n_in,
                              void* d_out, int out_size, void* d_ws, size_t ws_size,
                              hipStream_t stream) {
    const float* x   = (const float*)d_in[0];
    const float* gw  = (const float*)d_in[1];
    const float* W1  = (const float*)d_in[2];
    const float* W2  = (const float*)d_in[3];
    const float* Ws1 = (const float*)d_in[4];
    const float* Ws2 = (const float*)d_in[5];
    float* out = (float*)d_out;

    char* ws = (char*)d_ws;
    int*   counts  = (int*)(ws + 0);
    int*   cursor  = (int*)(ws + 64);
    int*   off     = (int*)(ws + 128);
    int*   tileoff = (int*)(ws + 192);
    float* imp     = (float*)(ws + 256);
    int*   tki     = (int*)(ws + 320);                    // 32768 B
    float* tkv     = (float*)(ws + 33088);                // 32768 B
    int*   list    = (int*)(ws + 65856);                  // 49152 B
    float* wgt     = (float*)(ws + 115008);               // 49152 B
    // big regions (bytes):
    //   xb  @ 164352 : 16,777,216
    //   Wt1 @ 16,941,568 : 51,904,512   (9 x 1408 x 2048 bf16)
    //   h1  @ 68,846,080 : 34,603,008   (12288 x 1408 bf16)
    //   Wt2 @ 164352 (aliases xb+Wt1 after fc1) : 51,904,512
    u16* xb  = (u16*)(ws + 164352);
    u16* wt1 = (u16*)(ws + 16941568ULL);
    u16* h1  = (u16*)(ws + 68846080ULL);
    u16* wt2 = (u16*)(ws + 164352);

    hipMemsetAsync(d_out, 0, (size_t)out_size * sizeof(float), stream);
    hipMemsetAsync(d_ws, 0, 320, stream);

    router_kernel<<<NT / 4, 256, 0, stream>>>(x, gw, counts, imp, tki, tkv);
    prep_kernel<<<1, 64, 0, stream>>>(counts, imp, off, tileoff, out + (size_t)NT * HD);
    scatter_kernel<<<NT / 256, 256, 0, stream>>>(tki, tkv, off, cursor, list, wgt);

    convx_kernel<<<NT * HD / 8 / 256, 256, 0, stream>>>(x, xb);
    transw_kernel<<<dim3(ID / 64, HD / 64, NE), 256, 0, stream>>>(W1, wt1, HD, ID);
    transw_kernel<<<dim3(ID / 64, HD / 64, 1), 256, 0, stream>>>(Ws1, wt1 + (size_t)NE * ID * HD, HD, ID);

    fc1_kernel<<<dim3(ID / BN, MT_MAX), 256, 0, stream>>>(xb, wt1, off, tileoff, list, h1);

    // Wt2 overwrites xb/Wt1 (both dead after fc1); stream order guarantees safety
    transw_kernel<<<dim3(HD / 64, ID / 64, NE), 256, 0, stream>>>(W2, wt2, ID, HD);
    transw_kernel<<<dim3(HD / 64, ID / 64, 1), 256, 0, stream>>>(Ws2, wt2 + (size_t)NE * ID * HD, ID, HD);

    fc2_kernel<<<dim3(HD / BN, MT_MAX), 256, 0, stream>>>(h1, wt2, off, tileoff, list, wgt, out);
}

// Round 3
// 434.592 us; speedup vs baseline: 1.9756x; 1.5285x over previous
//
#include <hip/hip_runtime.h>
#include <hip/hip_bf16.h>

#define NT 4096          // B*T tokens
#define HD 2048          // hidden
#define NE 8             // experts
#define TOPK 2
#define ID 1408          // intermediate
#define NG 9             // 8 experts + shared
#define NPAIR (NT*TOPK + NT)   // 12288 rows total
#define BM 128
#define BN 128
#define BK 64
#define MT_MAX 104       // max sum of ceil(cnt/128) over groups (<=71) + 32 shared

typedef unsigned short u16;
typedef unsigned int u32;
typedef unsigned long long u64;
typedef __attribute__((ext_vector_type(8))) short bf16x8;
typedef __attribute__((ext_vector_type(4))) float f32x4;

__device__ __forceinline__ u16 f2bf(float f) {
    u32 u = __builtin_bit_cast(u32, f);
    u += 0x7FFFu + ((u >> 16) & 1u);   // round-to-nearest-even
    return (u16)(u >> 16);
}

// async global->LDS, 16B per lane; lds base must be wave-uniform
typedef __attribute__((address_space(1))) const void gas_void;
typedef __attribute__((address_space(3))) void las_void;
__device__ __forceinline__ void gl_lds16(const void* g, void* l) {
    __builtin_amdgcn_global_load_lds((gas_void*)(u64)g, (las_void*)(u32)(u64)l, 16, 0, 0);
}

// ---------------- router: logits -> softmax -> top2 + importance/counts ----
__global__ void router_kernel(const float* __restrict__ x, const float* __restrict__ gw,
                              int* __restrict__ counts, float* __restrict__ imp,
                              int* __restrict__ tki, float* __restrict__ tkv) {
    __shared__ float s_imp[NE];
    __shared__ int s_cnt[NE];
    if (threadIdx.x < NE) { s_imp[threadIdx.x] = 0.f; s_cnt[threadIdx.x] = 0; }
    int w = threadIdx.x >> 6, lane = threadIdx.x & 63;
    int t = blockIdx.x * 4 + w;
    float acc[NE];
#pragma unroll
    for (int e = 0; e < NE; e++) acc[e] = 0.f;
    const float* xr = x + (size_t)t * HD;
    for (int i = 0; i < HD / 64; i++) {
        float xv = xr[lane + 64 * i];
#pragma unroll
        for (int e = 0; e < NE; e++) acc[e] += xv * gw[e * HD + lane + 64 * i];
    }
#pragma unroll
    for (int e = 0; e < NE; e++) {
#pragma unroll
        for (int o = 32; o >= 1; o >>= 1) acc[e] += __shfl_xor(acc[e], o, 64);
    }
    __syncthreads();
    if (lane == 0) {
        float mx = acc[0];
        for (int e = 1; e < NE; e++) mx = fmaxf(mx, acc[e]);
        float p[NE], sum = 0.f;
        for (int e = 0; e < NE; e++) { p[e] = expf(acc[e] - mx); sum += p[e]; }
        float inv = 1.f / sum;
        for (int e = 0; e < NE; e++) p[e] *= inv;
        int i1 = 0;
        for (int e = 1; e < NE; e++) if (p[e] > p[i1]) i1 = e;
        int i2 = (i1 == 0) ? 1 : 0;
        for (int e = 0; e < NE; e++) if (e != i1 && p[e] > p[i2]) i2 = e;
        tki[t * 2 + 0] = i1; tkv[t * 2 + 0] = p[i1];
        tki[t * 2 + 1] = i2; tkv[t * 2 + 1] = p[i2];
        for (int e = 0; e < NE; e++) atomicAdd(&s_imp[e], p[e]);
        atomicAdd(&s_cnt[i1], 1); atomicAdd(&s_cnt[i2], 1);
    }
    __syncthreads();
    if (threadIdx.x < NE) {
        atomicAdd(&imp[threadIdx.x], s_imp[threadIdx.x]);
        atomicAdd(&counts[threadIdx.x], s_cnt[threadIdx.x]);
    }
}

// ---------------- prep: offsets, tile offsets (BM=128), aux loss ------------
__global__ void prep_kernel(const int* __restrict__ counts, const float* __restrict__ imp,
                            int* __restrict__ off, int* __restrict__ tileoff,
                            float* __restrict__ out_aux) {
    if (threadIdx.x == 0 && blockIdx.x == 0) {
        int o = 0, to = 0;
        for (int g = 0; g < NG; g++) {
            int c = (g < NE) ? counts[g] : NT;
            off[g] = o; tileoff[g] = to;
            o += c; to += (c + BM - 1) / BM;
        }
        off[NG] = o; tileoff[NG] = to;
        float aux = 0.f;
        for (int e = 0; e < NE; e++)
            aux += (imp[e] / (float)NT) * ((float)counts[e] / (float)(NT * TOPK));
        *out_aux = aux * (float)NE;
    }
}

// ---------------- scatter: build per-group token lists ----------------------
__global__ void scatter_kernel(const int* __restrict__ tki, const float* __restrict__ tkv,
                               const int* __restrict__ off, int* __restrict__ cursor,
                               int* __restrict__ list, float* __restrict__ wgt) {
    int t = blockIdx.x * blockDim.x + threadIdx.x;
    if (t >= NT) return;
#pragma unroll
    for (int k = 0; k < TOPK; k++) {
        int e = tki[t * 2 + k];
        int pos = atomicAdd(&cursor[e], 1);
        list[off[e] + pos] = t;
        wgt[off[e] + pos] = tkv[t * 2 + k];
    }
    list[off[NE] + t] = t;
    wgt[off[NE] + t] = 1.0f;
}

// ---------------- convert x -> bf16 with k-frag perm within 64-blocks -------
// perm: k = h*32+s*16+q*4+r  ->  c = h*32+q*8+s*4+r
__global__ void convx_kernel(const float* __restrict__ x, u16* __restrict__ xb) {
    int c = blockIdx.x * 256 + threadIdx.x;       // chunk of 8 bf16
    int t = c >> 8;                                // 256 chunks per token
    int cc = c & 255;
    int b64 = cc >> 3, j = cc & 7;
    int h = j >> 2, q = j & 3;
    size_t base = (size_t)t * HD + b64 * 64 + h * 32 + q * 4;
    float4 v0 = *(const float4*)(x + base);
    float4 v1 = *(const float4*)(x + base + 16);
    ushort4 o0, o1;
    o0.x = f2bf(v0.x); o0.y = f2bf(v0.y); o0.z = f2bf(v0.z); o0.w = f2bf(v0.w);
    o1.x = f2bf(v1.x); o1.y = f2bf(v1.y); o1.z = f2bf(v1.z); o1.w = f2bf(v1.w);
    uint4 o;
    o.x = (u32)o0.x | ((u32)o0.y << 16); o.y = (u32)o0.z | ((u32)o0.w << 16);
    o.z = (u32)o1.x | ((u32)o1.y << 16); o.w = (u32)o1.z | ((u32)o1.w << 16);
    *(uint4*)(xb + (size_t)t * HD + b64 * 64 + j * 8) = o;
}

// ---------------- transpose+convert weights: [K][N] f32 -> [N][K'] bf16 -----
__global__ void transw_kernel(const float* __restrict__ src, u16* __restrict__ dst,
                              int K, int N) {
    int e = blockIdx.z;
    src += (size_t)e * K * N;
    dst += (size_t)e * N * K;
    int k0 = blockIdx.y * 64, n0 = blockIdx.x * 64;
    __shared__ u16 Lt[64][68];    // [n][k], padded
    int tid = threadIdx.x;
#pragma unroll
    for (int i = 0; i < 4; i++) {
        int idx = i * 256 + tid;
        int kl = idx >> 4, nq = (idx & 15) * 4;
        float4 v = *(const float4*)(src + (size_t)(k0 + kl) * N + n0 + nq);
        Lt[nq + 0][kl] = f2bf(v.x); Lt[nq + 1][kl] = f2bf(v.y);
        Lt[nq + 2][kl] = f2bf(v.z); Lt[nq + 3][kl] = f2bf(v.w);
    }
    __syncthreads();
#pragma unroll
    for (int c2 = 0; c2 < 2; c2++) {
        int cid = tid * 2 + c2;
        int nr = cid >> 3, j = cid & 7;
        int h = j >> 2, q = j & 3;
        int kb = h * 32 + q * 4;
        uint2 lo = *(const uint2*)&Lt[nr][kb];
        uint2 hi = *(const uint2*)&Lt[nr][kb + 16];
        uint4 o; o.x = lo.x; o.y = lo.y; o.z = hi.x; o.w = hi.y;
        *(uint4*)(dst + (size_t)(n0 + nr) * K + k0 + j * 8) = o;
    }
}

// ---------------- fc1: h1 = SiLU(xb_gathered @ Wt1_g^T), perm'd bf16 out ----
// LDS layout: linear [128][64] u16, but each row's eight 16B chunks are
// XOR-swizzled: chunk c stored at slot c ^ (row&7). Achieved by pre-swizzling
// the per-lane GLOBAL source chunk (gl_lds writes linearly), compensated on read.
__global__ __launch_bounds__(256) void fc1_kernel(
    const u16* __restrict__ xb, const u16* __restrict__ Wt1,
    const int* __restrict__ off, const int* __restrict__ tileoff,
    const int* __restrict__ list, u16* __restrict__ h1) {
    __shared__ u16 As[BM * BK];
    __shared__ u16 Bs[BN * BK];
    int mt = blockIdx.y;
    int g = -1, gto = 0;
#pragma unroll
    for (int gg = 0; gg < NG; gg++)
        if (mt >= tileoff[gg] && mt < tileoff[gg + 1]) { g = gg; gto = tileoff[gg]; }
    if (g < 0) return;
    int goff = off[g], cnt = off[g + 1] - goff;
    int row0 = (mt - gto) * BM;
    const u16* Wb = Wt1 + (size_t)g * (ID * HD);
    int n0 = blockIdx.x * BN;
    int tid = threadIdx.x, lane = tid & 63, w = tid >> 6;
    int lm = lane >> 3;                              // row within 8-row group
    int lc = (((lane & 7) ^ lm) << 3);               // swizzled source chunk
    const u16* pa[4]; const u16* pb[4];
#pragma unroll
    for (int i = 0; i < 4; i++) {
        int c = i * 4 + w;
        int r = row0 + c * 8 + lm;
        r = (r < cnt) ? r : (cnt - 1);
        pa[i] = xb + (size_t)list[goff + r] * HD + lc;
        pb[i] = Wb + (size_t)(n0 + c * 8 + lm) * HD + lc;
    }
    int wr = w >> 1, wc = w & 1;
    int lr = lane & 15, l7 = lane & 7, q2 = lane >> 4;
    f32x4 acc[4][4] = {};
    for (int k0 = 0; k0 < HD; k0 += BK) {
#pragma unroll
        for (int i = 0; i < 4; i++) {
            gl_lds16(pa[i], As + (i * 4 + w) * 512);
            gl_lds16(pb[i], Bs + (i * 4 + w) * 512);
            pa[i] += BK; pb[i] += BK;
        }
        __syncthreads();
#pragma unroll
        for (int kc = 0; kc < 8; kc += 4) {          // chunk base = kk/8
            int slot = ((kc + q2) ^ l7) << 3;        // swizzled read chunk
            bf16x8 a[4], b[4];
#pragma unroll
            for (int f = 0; f < 4; f++) {
                a[f] = __builtin_bit_cast(bf16x8, *(const uint4*)&As[(wr * 64 + f * 16 + lr) * BK + slot]);
                b[f] = __builtin_bit_cast(bf16x8, *(const uint4*)&Bs[(wc * 64 + f * 16 + lr) * BK + slot]);
            }
#pragma unroll
            for (int mf = 0; mf < 4; mf++)
#pragma unroll
                for (int nf = 0; nf < 4; nf++)
                    acc[mf][nf] = __builtin_amdgcn_mfma_f32_16x16x32_bf16(a[mf], b[nf], acc[mf][nf], 0, 0, 0);
        }
        __syncthreads();
    }
    // epilogue: SiLU, store h1 with k-frag perm within each 64-col block
    int q4 = q2 * 4;
    int cl = ((lr >> 2) << 3) + (lr & 3);
#pragma unroll
    for (int mf = 0; mf < 4; mf++)
#pragma unroll
        for (int reg = 0; reg < 4; reg++) {
            int r = row0 + wr * 64 + mf * 16 + q4 + reg;
            if (r < cnt) {
                size_t rb = (size_t)(goff + r) * ID + n0 + wc * 64;
#pragma unroll
                for (int nf = 0; nf < 4; nf++) {
                    float v = acc[mf][nf][reg];
                    h1[rb + ((nf >> 1) << 5) + ((nf & 1) << 2) + cl] = f2bf(v / (1.f + __expf(-v)));
                }
            }
        }
}

// ---------------- fc2: y[token] += wgt * (h1 @ Wt2_g^T) ---------------------
__global__ __launch_bounds__(256) void fc2_kernel(
    const u16* __restrict__ h1, const u16* __restrict__ Wt2,
    const int* __restrict__ off, const int* __restrict__ tileoff,
    const int* __restrict__ list, const float* __restrict__ wgt,
    float* __restrict__ y) {
    __shared__ u16 As[BM * BK];
    __shared__ u16 Bs[BN * BK];
    int mt = blockIdx.y;
    int g = -1, gto = 0;
#pragma unroll
    for (int gg = 0; gg < NG; gg++)
        if (mt >= tileoff[gg] && mt < tileoff[gg + 1]) { g = gg; gto = tileoff[gg]; }
    if (g < 0) return;
    int goff = off[g], cnt = off[g + 1] - goff;
    int row0 = (mt - gto) * BM;
    const u16* Wb = Wt2 + (size_t)g * (ID * HD);
    int n0 = blockIdx.x * BN;
    int tid = threadIdx.x, lane = tid & 63, w = tid >> 6;
    int lm = lane >> 3;
    int lc = (((lane & 7) ^ lm) << 3);               // swizzled source chunk
    const u16* pa[4]; const u16* pb[4];
#pragma unroll
    for (int i = 0; i < 4; i++) {
        int c = i * 4 + w;
        int r = row0 + c * 8 + lm;
        r = (r < cnt) ? r : (cnt - 1);
        pa[i] = h1 + (size_t)(goff + r) * ID + lc;           // slot-indexed, perm'd
        pb[i] = Wb + (size_t)(n0 + c * 8 + lm) * ID + lc;    // perm'd weights
    }
    int wr = w >> 1, wc = w & 1;
    int lr = lane & 15, l7 = lane & 7, q2 = lane >> 4;
    f32x4 acc[4][4] = {};
    for (int k0 = 0; k0 < ID; k0 += BK) {    // 22 iters exact
#pragma unroll
        for (int i = 0; i < 4; i++) {
            gl_lds16(pa[i], As + (i * 4 + w) * 512);
            gl_lds16(pb[i], Bs + (i * 4 + w) * 512);
            pa[i] += BK; pb[i] += BK;
        }
        __syncthreads();
#pragma unroll
        for (int kc = 0; kc < 8; kc += 4) {
            int slot = ((kc + q2) ^ l7) << 3;
            bf16x8 a[4], b[4];
#pragma unroll
            for (int f = 0; f < 4; f++) {
                a[f] = __builtin_bit_cast(bf16x8, *(const uint4*)&As[(wr * 64 + f * 16 + lr) * BK + slot]);
                b[f] = __builtin_bit_cast(bf16x8, *(const uint4*)&Bs[(wc * 64 + f * 16 + lr) * BK + slot]);
            }
#pragma unroll
            for (int mf = 0; mf < 4; mf++)
#pragma unroll
                for (int nf = 0; nf < 4; nf++)
                    acc[mf][nf] = __builtin_amdgcn_mfma_f32_16x16x32_bf16(a[mf], b[nf], acc[mf][nf], 0, 0, 0);
        }
        __syncthreads();
    }
    int q4 = q2 * 4;
#pragma unroll
    for (int mf = 0; mf < 4; mf++)
#pragma unroll
        for (int reg = 0; reg < 4; reg++) {
            int r = row0 + wr * 64 + mf * 16 + q4 + reg;
            if (r < cnt) {
                int slot = goff + r;
                int tok = list[slot];
                float wv = wgt[slot];
                float* yr = y + (size_t)tok * HD + n0 + wc * 64;
#pragma unroll
                for (int nf = 0; nf < 4; nf++)
                    atomicAdd(yr + nf * 16 + lr, acc[mf][nf][reg] * wv);
            }
        }
}

// ---------------- launch -----------------------------------------------------
extern "C" void kernel_launch(void* const* d_in, const int* in_sizes, int n_in,
                              void* d_out, int out_size, void* d_ws, size_t ws_size,
                              hipStream_t stream) {
    const float* x   = (const float*)d_in[0];
    const float* gw  = (const float*)d_in[1];
    const float* W1  = (const float*)d_in[2];
    const float* W2  = (const float*)d_in[3];
    const float* Ws1 = (const float*)d_in[4];
    const float* Ws2 = (const float*)d_in[5];
    float* out = (float*)d_out;

    char* ws = (char*)d_ws;
    int*   counts  = (int*)(ws + 0);
    int*   cursor  = (int*)(ws + 64);
    int*   off     = (int*)(ws + 128);
    int*   tileoff = (int*)(ws + 192);
    float* imp     = (float*)(ws + 256);
    int*   tki     = (int*)(ws + 320);                    // 32768 B
    float* tkv     = (float*)(ws + 33088);                // 32768 B
    int*   list    = (int*)(ws + 65856);                  // 49152 B
    float* wgt     = (float*)(ws + 115008);               // 49152 B
    // big regions (bytes):
    //   xb  @ 164352 : 16,777,216
    //   Wt1 @ 16,941,568 : 51,904,512   (9 x 1408 x 2048 bf16)
    //   h1  @ 68,846,080 : 34,603,008   (12288 x 1408 bf16, perm'd cols)
    //   Wt2 @ 164352 (aliases xb+Wt1 after fc1) : 51,904,512
    u16* xb  = (u16*)(ws + 164352);
    u16* wt1 = (u16*)(ws + 16941568ULL);
    u16* h1  = (u16*)(ws + 68846080ULL);
    u16* wt2 = (u16*)(ws + 164352);

    hipMemsetAsync(d_out, 0, (size_t)out_size * sizeof(float), stream);
    hipMemsetAsync(d_ws, 0, 320, stream);

    router_kernel<<<NT / 4, 256, 0, stream>>>(x, gw, counts, imp, tki, tkv);
    prep_kernel<<<1, 64, 0, stream>>>(counts, imp, off, tileoff, out + (size_t)NT * HD);
    scatter_kernel<<<NT / 256, 256, 0, stream>>>(tki, tkv, off, cursor, list, wgt);

    convx_kernel<<<NT * HD / 8 / 256, 256, 0, stream>>>(x, xb);
    transw_kernel<<<dim3(ID / 64, HD / 64, NE), 256, 0, stream>>>(W1, wt1, HD, ID);
    transw_kernel<<<dim3(ID / 64, HD / 64, 1), 256, 0, stream>>>(Ws1, wt1 + (size_t)NE * ID * HD, HD, ID);

    fc1_kernel<<<dim3(ID / BN, MT_MAX), 256, 0, stream>>>(xb, wt1, off, tileoff, list, h1);

    // Wt2 overwrites xb/Wt1 (both dead after fc1); stream order guarantees safety
    transw_kernel<<<dim3(HD / 64, ID / 64, NE), 256, 0, stream>>>(W2, wt2, ID, HD);
    transw_kernel<<<dim3(HD / 64, ID / 64, 1), 256, 0, stream>>>(Ws2, wt2 + (size_t)NE * ID * HD, ID, HD);

    fc2_kernel<<<dim3(HD / BN, MT_MAX), 256, 0, stream>>>(h1, wt2, off, tileoff, list, wgt, out);
}

// Round 4
// 388.145 us; speedup vs baseline: 2.2120x; 1.1197x over previous
//
#include <hip/hip_runtime.h>
#include <hip/hip_bf16.h>

#define NT 4096          // B*T tokens
#define HD 2048          // hidden
#define NE 8             // experts
#define TOPK 2
#define ID 1408          // intermediate
#define NG 9             // 8 experts + shared
#define NPAIR (NT*TOPK + NT)   // 12288 rows total
#define BM 128
#define BN 128
#define BK 64
#define MT_MAX 104       // max sum of ceil(cnt/128) over groups (<=72) + 32 shared

typedef unsigned short u16;
typedef unsigned int u32;
typedef unsigned long long u64;
typedef __attribute__((ext_vector_type(8))) short bf16x8;
typedef __attribute__((ext_vector_type(4))) float f32x4;

__device__ __forceinline__ u16 f2bf(float f) {
    u32 u = __builtin_bit_cast(u32, f);
    u += 0x7FFFu + ((u >> 16) & 1u);   // round-to-nearest-even
    return (u16)(u >> 16);
}

// async global->LDS, 16B per lane; lds base must be wave-uniform
typedef __attribute__((address_space(1))) const void gas_void;
typedef __attribute__((address_space(3))) void las_void;
__device__ __forceinline__ void gl_lds16(const void* g, void* l) {
    __builtin_amdgcn_global_load_lds((gas_void*)(u64)g, (las_void*)(u32)(u64)l, 16, 0, 0);
}

// ---------------- router: logits -> softmax -> top2 + importance/counts ----
__global__ void router_kernel(const float* __restrict__ x, const float* __restrict__ gw,
                              int* __restrict__ counts, float* __restrict__ imp,
                              int* __restrict__ tki, float* __restrict__ tkv) {
    __shared__ float s_imp[NE];
    __shared__ int s_cnt[NE];
    if (threadIdx.x < NE) { s_imp[threadIdx.x] = 0.f; s_cnt[threadIdx.x] = 0; }
    int w = threadIdx.x >> 6, lane = threadIdx.x & 63;
    int t = blockIdx.x * 4 + w;
    float acc[NE];
#pragma unroll
    for (int e = 0; e < NE; e++) acc[e] = 0.f;
    const float* xr = x + (size_t)t * HD;
    for (int i = 0; i < HD / 64; i++) {
        float xv = xr[lane + 64 * i];
#pragma unroll
        for (int e = 0; e < NE; e++) acc[e] += xv * gw[e * HD + lane + 64 * i];
    }
#pragma unroll
    for (int e = 0; e < NE; e++) {
#pragma unroll
        for (int o = 32; o >= 1; o >>= 1) acc[e] += __shfl_xor(acc[e], o, 64);
    }
    __syncthreads();
    if (lane == 0) {
        float mx = acc[0];
        for (int e = 1; e < NE; e++) mx = fmaxf(mx, acc[e]);
        float p[NE], sum = 0.f;
        for (int e = 0; e < NE; e++) { p[e] = expf(acc[e] - mx); sum += p[e]; }
        float inv = 1.f / sum;
        for (int e = 0; e < NE; e++) p[e] *= inv;
        int i1 = 0;
        for (int e = 1; e < NE; e++) if (p[e] > p[i1]) i1 = e;
        int i2 = (i1 == 0) ? 1 : 0;
        for (int e = 0; e < NE; e++) if (e != i1 && p[e] > p[i2]) i2 = e;
        tki[t * 2 + 0] = i1; tkv[t * 2 + 0] = p[i1];
        tki[t * 2 + 1] = i2; tkv[t * 2 + 1] = p[i2];
        for (int e = 0; e < NE; e++) atomicAdd(&s_imp[e], p[e]);
        atomicAdd(&s_cnt[i1], 1); atomicAdd(&s_cnt[i2], 1);
    }
    __syncthreads();
    if (threadIdx.x < NE) {
        atomicAdd(&imp[threadIdx.x], s_imp[threadIdx.x]);
        atomicAdd(&counts[threadIdx.x], s_cnt[threadIdx.x]);
    }
}

// ---------------- prep: offsets, tile offsets (BM=128), aux loss ------------
__global__ void prep_kernel(const int* __restrict__ counts, const float* __restrict__ imp,
                            int* __restrict__ off, int* __restrict__ tileoff,
                            float* __restrict__ out_aux) {
    if (threadIdx.x == 0 && blockIdx.x == 0) {
        int o = 0, to = 0;
        for (int g = 0; g < NG; g++) {
            int c = (g < NE) ? counts[g] : NT;
            off[g] = o; tileoff[g] = to;
            o += c; to += (c + BM - 1) / BM;
        }
        off[NG] = o; tileoff[NG] = to;
        float aux = 0.f;
        for (int e = 0; e < NE; e++)
            aux += (imp[e] / (float)NT) * ((float)counts[e] / (float)(NT * TOPK));
        *out_aux = aux * (float)NE;
    }
}

// ---------------- scatter: build per-group token lists ----------------------
__global__ void scatter_kernel(const int* __restrict__ tki, const float* __restrict__ tkv,
                               const int* __restrict__ off, int* __restrict__ cursor,
                               int* __restrict__ list, float* __restrict__ wgt) {
    int t = blockIdx.x * blockDim.x + threadIdx.x;
    if (t >= NT) return;
#pragma unroll
    for (int k = 0; k < TOPK; k++) {
        int e = tki[t * 2 + k];
        int pos = atomicAdd(&cursor[e], 1);
        list[off[e] + pos] = t;
        wgt[off[e] + pos] = tkv[t * 2 + k];
    }
    list[off[NE] + t] = t;
    wgt[off[NE] + t] = 1.0f;
}

// ---------------- convert x -> bf16 with k-frag perm within 64-blocks -------
// perm: k = h*32+s*16+q*4+r  ->  c = h*32+q*8+s*4+r
__global__ void convx_kernel(const float* __restrict__ x, u16* __restrict__ xb) {
    int c = blockIdx.x * 256 + threadIdx.x;       // chunk of 8 bf16
    int t = c >> 8;                                // 256 chunks per token
    int cc = c & 255;
    int b64 = cc >> 3, j = cc & 7;
    int h = j >> 2, q = j & 3;
    size_t base = (size_t)t * HD + b64 * 64 + h * 32 + q * 4;
    float4 v0 = *(const float4*)(x + base);
    float4 v1 = *(const float4*)(x + base + 16);
    ushort4 o0, o1;
    o0.x = f2bf(v0.x); o0.y = f2bf(v0.y); o0.z = f2bf(v0.z); o0.w = f2bf(v0.w);
    o1.x = f2bf(v1.x); o1.y = f2bf(v1.y); o1.z = f2bf(v1.z); o1.w = f2bf(v1.w);
    uint4 o;
    o.x = (u32)o0.x | ((u32)o0.y << 16); o.y = (u32)o0.z | ((u32)o0.w << 16);
    o.z = (u32)o1.x | ((u32)o1.y << 16); o.w = (u32)o1.z | ((u32)o1.w << 16);
    *(uint4*)(xb + (size_t)t * HD + b64 * 64 + j * 8) = o;
}

// ---------------- transpose+convert weights: [K][N] f32 -> [N][K'] bf16 -----
__global__ void transw_kernel(const float* __restrict__ src, u16* __restrict__ dst,
                              int K, int N) {
    int e = blockIdx.z;
    src += (size_t)e * K * N;
    dst += (size_t)e * N * K;
    int k0 = blockIdx.y * 64, n0 = blockIdx.x * 64;
    __shared__ u16 Lt[64][68];    // [n][k], padded
    int tid = threadIdx.x;
#pragma unroll
    for (int i = 0; i < 4; i++) {
        int idx = i * 256 + tid;
        int kl = idx >> 4, nq = (idx & 15) * 4;
        float4 v = *(const float4*)(src + (size_t)(k0 + kl) * N + n0 + nq);
        Lt[nq + 0][kl] = f2bf(v.x); Lt[nq + 1][kl] = f2bf(v.y);
        Lt[nq + 2][kl] = f2bf(v.z); Lt[nq + 3][kl] = f2bf(v.w);
    }
    __syncthreads();
#pragma unroll
    for (int c2 = 0; c2 < 2; c2++) {
        int cid = tid * 2 + c2;
        int nr = cid >> 3, j = cid & 7;
        int h = j >> 2, q = j & 3;
        int kb = h * 32 + q * 4;
        uint2 lo = *(const uint2*)&Lt[nr][kb];
        uint2 hi = *(const uint2*)&Lt[nr][kb + 16];
        uint4 o; o.x = lo.x; o.y = lo.y; o.z = hi.x; o.w = hi.y;
        *(uint4*)(dst + (size_t)(n0 + nr) * K + k0 + j * 8) = o;
    }
}

// ---------------- fc1: h1 = SiLU(xb_gathered @ Wt1_g^T), perm'd bf16 out ----
// 2-phase double-buffered: STAGE(t+1) issued before compute(t), one barrier
// per K-step (its implicit vmcnt(0) drain is overlapped by the MFMA work).
// LDS XOR-swizzle as round 3 (pre-swizzled global source chunk).
__global__ __launch_bounds__(256) void fc1_kernel(
    const u16* __restrict__ xb, const u16* __restrict__ Wt1,
    const int* __restrict__ off, const int* __restrict__ tileoff,
    const int* __restrict__ list, u16* __restrict__ h1) {
    __shared__ u16 S[4 * 8192];   // As0|Bs0|As1|Bs1 (16KB each), 64KB total
    // XCD-chunked swizzle (nwg = 11*104 = 1144, divisible by 8)
    int nwg = gridDim.x * gridDim.y;
    int orig = blockIdx.y * gridDim.x + blockIdx.x;
    int wg = (orig & 7) * (nwg >> 3) + (orig >> 3);
    int bx = wg % gridDim.x, mt = wg / gridDim.x;

    int g = -1, gto = 0;
#pragma unroll
    for (int gg = 0; gg < NG; gg++)
        if (mt >= tileoff[gg] && mt < tileoff[gg + 1]) { g = gg; gto = tileoff[gg]; }
    if (g < 0) return;
    int goff = off[g], cnt = off[g + 1] - goff;
    int row0 = (mt - gto) * BM;
    const u16* Wb = Wt1 + (size_t)g * (ID * HD);
    int n0 = bx * BN;
    int tid = threadIdx.x, lane = tid & 63, w = tid >> 6;
    int lm = lane >> 3;                              // row within 8-row group
    int lc = (((lane & 7) ^ lm) << 3);               // swizzled source chunk
    const u16* pa[4]; const u16* pb[4];
#pragma unroll
    for (int i = 0; i < 4; i++) {
        int c = i * 4 + w;
        int r = row0 + c * 8 + lm;
        r = (r < cnt) ? r : (cnt - 1);
        pa[i] = xb + (size_t)list[goff + r] * HD + lc;
        pb[i] = Wb + (size_t)(n0 + c * 8 + lm) * HD + lc;
    }
    int wr = w >> 1, wc = w & 1;
    int lr = lane & 15, l7 = lane & 7, q2 = lane >> 4;
    f32x4 acc[4][4] = {};

    auto stage = [&](int b) {
        u16* A = S + b * 16384;
        u16* B = A + 8192;
#pragma unroll
        for (int i = 0; i < 4; i++) {
            gl_lds16(pa[i], A + (i * 4 + w) * 512);
            gl_lds16(pb[i], B + (i * 4 + w) * 512);
            pa[i] += BK; pb[i] += BK;
        }
    };
    auto compute = [&](int b) {
        const u16* A = S + b * 16384;
        const u16* B = A + 8192;
#pragma unroll
        for (int kc = 0; kc < 8; kc += 4) {
            int slot = ((kc + q2) ^ l7) << 3;
            bf16x8 a[4], bb[4];
#pragma unroll
            for (int f = 0; f < 4; f++) {
                a[f]  = __builtin_bit_cast(bf16x8, *(const uint4*)&A[(wr * 64 + f * 16 + lr) * BK + slot]);
                bb[f] = __builtin_bit_cast(bf16x8, *(const uint4*)&B[(wc * 64 + f * 16 + lr) * BK + slot]);
            }
#pragma unroll
            for (int mf = 0; mf < 4; mf++)
#pragma unroll
                for (int nf = 0; nf < 4; nf++)
                    acc[mf][nf] = __builtin_amdgcn_mfma_f32_16x16x32_bf16(a[mf], bb[nf], acc[mf][nf], 0, 0, 0);
        }
    };

    stage(0);
    __syncthreads();
    int cur = 0;
    for (int t = 1; t < HD / BK; ++t) {   // 32 K-steps total
        stage(cur ^ 1);
        compute(cur);
        __syncthreads();
        cur ^= 1;
    }
    compute(cur);

    // epilogue: SiLU, store h1 with k-frag perm within each 64-col block
    int q4 = q2 * 4;
    int cl = ((lr >> 2) << 3) + (lr & 3);
#pragma unroll
    for (int mf = 0; mf < 4; mf++)
#pragma unroll
        for (int reg = 0; reg < 4; reg++) {
            int r = row0 + wr * 64 + mf * 16 + q4 + reg;
            if (r < cnt) {
                size_t rb = (size_t)(goff + r) * ID + n0 + wc * 64;
#pragma unroll
                for (int nf = 0; nf < 4; nf++) {
                    float v = acc[mf][nf][reg];
                    h1[rb + ((nf >> 1) << 5) + ((nf & 1) << 2) + cl] = f2bf(v / (1.f + __expf(-v)));
                }
            }
        }
}

// ---------------- fc2: y[token] += wgt * (h1 @ Wt2_g^T) ---------------------
__global__ __launch_bounds__(256) void fc2_kernel(
    const u16* __restrict__ h1, const u16* __restrict__ Wt2,
    const int* __restrict__ off, const int* __restrict__ tileoff,
    const int* __restrict__ list, const float* __restrict__ wgt,
    float* __restrict__ y) {
    __shared__ u16 S[4 * 8192];
    // XCD-chunked swizzle (nwg = 16*104 = 1664, divisible by 8)
    int nwg = gridDim.x * gridDim.y;
    int orig = blockIdx.y * gridDim.x + blockIdx.x;
    int wg = (orig & 7) * (nwg >> 3) + (orig >> 3);
    int bx = wg % gridDim.x, mt = wg / gridDim.x;

    int g = -1, gto = 0;
#pragma unroll
    for (int gg = 0; gg < NG; gg++)
        if (mt >= tileoff[gg] && mt < tileoff[gg + 1]) { g = gg; gto = tileoff[gg]; }
    if (g < 0) return;
    int goff = off[g], cnt = off[g + 1] - goff;
    int row0 = (mt - gto) * BM;
    const u16* Wb = Wt2 + (size_t)g * (ID * HD);
    int n0 = bx * BN;
    int tid = threadIdx.x, lane = tid & 63, w = tid >> 6;
    int lm = lane >> 3;
    int lc = (((lane & 7) ^ lm) << 3);
    const u16* pa[4]; const u16* pb[4];
#pragma unroll
    for (int i = 0; i < 4; i++) {
        int c = i * 4 + w;
        int r = row0 + c * 8 + lm;
        r = (r < cnt) ? r : (cnt - 1);
        pa[i] = h1 + (size_t)(goff + r) * ID + lc;           // slot-indexed, perm'd
        pb[i] = Wb + (size_t)(n0 + c * 8 + lm) * ID + lc;    // perm'd weights
    }
    int wr = w >> 1, wc = w & 1;
    int lr = lane & 15, l7 = lane & 7, q2 = lane >> 4;
    f32x4 acc[4][4] = {};

    auto stage = [&](int b) {
        u16* A = S + b * 16384;
        u16* B = A + 8192;
#pragma unroll
        for (int i = 0; i < 4; i++) {
            gl_lds16(pa[i], A + (i * 4 + w) * 512);
            gl_lds16(pb[i], B + (i * 4 + w) * 512);
            pa[i] += BK; pb[i] += BK;
        }
    };
    auto compute = [&](int b) {
        const u16* A = S + b * 16384;
        const u16* B = A + 8192;
#pragma unroll
        for (int kc = 0; kc < 8; kc += 4) {
            int slot = ((kc + q2) ^ l7) << 3;
            bf16x8 a[4], bb[4];
#pragma unroll
            for (int f = 0; f < 4; f++) {
                a[f]  = __builtin_bit_cast(bf16x8, *(const uint4*)&A[(wr * 64 + f * 16 + lr) * BK + slot]);
                bb[f] = __builtin_bit_cast(bf16x8, *(const uint4*)&B[(wc * 64 + f * 16 + lr) * BK + slot]);
            }
#pragma unroll
            for (int mf = 0; mf < 4; mf++)
#pragma unroll
                for (int nf = 0; nf < 4; nf++)
                    acc[mf][nf] = __builtin_amdgcn_mfma_f32_16x16x32_bf16(a[mf], bb[nf], acc[mf][nf], 0, 0, 0);
        }
    };

    stage(0);
    __syncthreads();
    int cur = 0;
    for (int t = 1; t < ID / BK; ++t) {   // 22 K-steps total
        stage(cur ^ 1);
        compute(cur);
        __syncthreads();
        cur ^= 1;
    }
    compute(cur);

    int q4 = q2 * 4;
#pragma unroll
    for (int mf = 0; mf < 4; mf++)
#pragma unroll
        for (int reg = 0; reg < 4; reg++) {
            int r = row0 + wr * 64 + mf * 16 + q4 + reg;
            if (r < cnt) {
                int slot = goff + r;
                int tok = list[slot];
                float wv = wgt[slot];
                float* yr = y + (size_t)tok * HD + n0 + wc * 64;
#pragma unroll
                for (int nf = 0; nf < 4; nf++)
                    atomicAdd(yr + nf * 16 + lr, acc[mf][nf][reg] * wv);
            }
        }
}

// ---------------- launch -----------------------------------------------------
extern "C" void kernel_launch(void* const* d_in, const int* in_sizes, int n_in,
                              void* d_out, int out_size, void* d_ws, size_t ws_size,
                              hipStream_t stream) {
    const float* x   = (const float*)d_in[0];
    const float* gw  = (const float*)d_in[1];
    const float* W1  = (const float*)d_in[2];
    const float* W2  = (const float*)d_in[3];
    const float* Ws1 = (const float*)d_in[4];
    const float* Ws2 = (const float*)d_in[5];
    float* out = (float*)d_out;

    char* ws = (char*)d_ws;
    int*   counts  = (int*)(ws + 0);
    int*   cursor  = (int*)(ws + 64);
    int*   off     = (int*)(ws + 128);
    int*   tileoff = (int*)(ws + 192);
    float* imp     = (float*)(ws + 256);
    int*   tki     = (int*)(ws + 320);                    // 32768 B
    float* tkv     = (float*)(ws + 33088);                // 32768 B
    int*   list    = (int*)(ws + 65856);                  // 49152 B
    float* wgt     = (float*)(ws + 115008);               // 49152 B
    // big regions (bytes):
    //   xb  @ 164352 : 16,777,216
    //   Wt1 @ 16,941,568 : 51,904,512   (9 x 1408 x 2048 bf16)
    //   h1  @ 68,846,080 : 34,603,008   (12288 x 1408 bf16, perm'd cols)
    //   Wt2 @ 164352 (aliases xb+Wt1 after fc1) : 51,904,512
    u16* xb  = (u16*)(ws + 164352);
    u16* wt1 = (u16*)(ws + 16941568ULL);
    u16* h1  = (u16*)(ws + 68846080ULL);
    u16* wt2 = (u16*)(ws + 164352);

    hipMemsetAsync(d_out, 0, (size_t)out_size * sizeof(float), stream);
    hipMemsetAsync(d_ws, 0, 320, stream);

    router_kernel<<<NT / 4, 256, 0, stream>>>(x, gw, counts, imp, tki, tkv);
    prep_kernel<<<1, 64, 0, stream>>>(counts, imp, off, tileoff, out + (size_t)NT * HD);
    scatter_kernel<<<NT / 256, 256, 0, stream>>>(tki, tkv, off, cursor, list, wgt);

    convx_kernel<<<NT * HD / 8 / 256, 256, 0, stream>>>(x, xb);
    transw_kernel<<<dim3(ID / 64, HD / 64, NE), 256, 0, stream>>>(W1, wt1, HD, ID);
    transw_kernel<<<dim3(ID / 64, HD / 64, 1), 256, 0, stream>>>(Ws1, wt1 + (size_t)NE * ID * HD, HD, ID);

    fc1_kernel<<<dim3(ID / BN, MT_MAX), 256, 0, stream>>>(xb, wt1, off, tileoff, list, h1);

    // Wt2 overwrites xb/Wt1 (both dead after fc1); stream order guarantees safety
    transw_kernel<<<dim3(HD / 64, ID / 64, NE), 256, 0, stream>>>(W2, wt2, ID, HD);
    transw_kernel<<<dim3(HD / 64, ID / 64, 1), 256, 0, stream>>>(Ws2, wt2 + (size_t)NE * ID * HD, ID, HD);

    fc2_kernel<<<dim3(HD / BN, MT_MAX), 256, 0, stream>>>(h1, wt2, off, tileoff, list, wgt, out);
}

// Round 5
// 386.368 us; speedup vs baseline: 2.2222x; 1.0046x over previous
//
#include <hip/hip_runtime.h>
#include <hip/hip_bf16.h>

#define NT 4096          // B*T tokens
#define HD 2048          // hidden
#define NE 8             // experts
#define TOPK 2
#define ID 1408          // intermediate
#define NG 9             // 8 experts + shared
#define NPAIR (NT*TOPK + NT)   // 12288 rows total
#define BM 128
#define BN 128
#define BK 64
#define MT_MAX 104       // max sum of ceil(cnt/128) over groups (<=72) + 32 shared

typedef unsigned short u16;
typedef unsigned int u32;
typedef unsigned long long u64;
typedef __attribute__((ext_vector_type(8))) short bf16x8;
typedef __attribute__((ext_vector_type(4))) float f32x4;

__device__ __forceinline__ u16 f2bf(float f) {
    u32 u = __builtin_bit_cast(u32, f);
    u += 0x7FFFu + ((u >> 16) & 1u);   // round-to-nearest-even
    return (u16)(u >> 16);
}

// async global->LDS, 16B per lane; lds base must be wave-uniform
typedef __attribute__((address_space(1))) const void gas_void;
typedef __attribute__((address_space(3))) void las_void;
__device__ __forceinline__ void gl_lds16(const void* g, void* l) {
    __builtin_amdgcn_global_load_lds((gas_void*)(u64)g, (las_void*)(u32)(u64)l, 16, 0, 0);
}

// ---------------- router: logits -> softmax -> top2 + importance/counts ----
__global__ void router_kernel(const float* __restrict__ x, const float* __restrict__ gw,
                              int* __restrict__ counts, float* __restrict__ imp,
                              int* __restrict__ tki, float* __restrict__ tkv) {
    __shared__ float s_imp[NE];
    __shared__ int s_cnt[NE];
    if (threadIdx.x < NE) { s_imp[threadIdx.x] = 0.f; s_cnt[threadIdx.x] = 0; }
    int w = threadIdx.x >> 6, lane = threadIdx.x & 63;
    int t = blockIdx.x * 4 + w;
    float acc[NE];
#pragma unroll
    for (int e = 0; e < NE; e++) acc[e] = 0.f;
    const float* xr = x + (size_t)t * HD;
    for (int i = 0; i < HD / 64; i++) {
        float xv = xr[lane + 64 * i];
#pragma unroll
        for (int e = 0; e < NE; e++) acc[e] += xv * gw[e * HD + lane + 64 * i];
    }
#pragma unroll
    for (int e = 0; e < NE; e++) {
#pragma unroll
        for (int o = 32; o >= 1; o >>= 1) acc[e] += __shfl_xor(acc[e], o, 64);
    }
    __syncthreads();
    if (lane == 0) {
        float mx = acc[0];
        for (int e = 1; e < NE; e++) mx = fmaxf(mx, acc[e]);
        float p[NE], sum = 0.f;
        for (int e = 0; e < NE; e++) { p[e] = expf(acc[e] - mx); sum += p[e]; }
        float inv = 1.f / sum;
        for (int e = 0; e < NE; e++) p[e] *= inv;
        int i1 = 0;
        for (int e = 1; e < NE; e++) if (p[e] > p[i1]) i1 = e;
        int i2 = (i1 == 0) ? 1 : 0;
        for (int e = 0; e < NE; e++) if (e != i1 && p[e] > p[i2]) i2 = e;
        tki[t * 2 + 0] = i1; tkv[t * 2 + 0] = p[i1];
        tki[t * 2 + 1] = i2; tkv[t * 2 + 1] = p[i2];
        for (int e = 0; e < NE; e++) atomicAdd(&s_imp[e], p[e]);
        atomicAdd(&s_cnt[i1], 1); atomicAdd(&s_cnt[i2], 1);
    }
    __syncthreads();
    if (threadIdx.x < NE) {
        atomicAdd(&imp[threadIdx.x], s_imp[threadIdx.x]);
        atomicAdd(&counts[threadIdx.x], s_cnt[threadIdx.x]);
    }
}

// ---------------- prep: offsets, tile offsets (BM=128), aux loss ------------
__global__ void prep_kernel(const int* __restrict__ counts, const float* __restrict__ imp,
                            int* __restrict__ off, int* __restrict__ tileoff,
                            float* __restrict__ out_aux) {
    if (threadIdx.x == 0 && blockIdx.x == 0) {
        int o = 0, to = 0;
        for (int g = 0; g < NG; g++) {
            int c = (g < NE) ? counts[g] : NT;
            off[g] = o; tileoff[g] = to;
            o += c; to += (c + BM - 1) / BM;
        }
        off[NG] = o; tileoff[NG] = to;
        float aux = 0.f;
        for (int e = 0; e < NE; e++)
            aux += (imp[e] / (float)NT) * ((float)counts[e] / (float)(NT * TOPK));
        *out_aux = aux * (float)NE;
    }
}

// ---------------- scatter: build per-group token lists ----------------------
__global__ void scatter_kernel(const int* __restrict__ tki, const float* __restrict__ tkv,
                               const int* __restrict__ off, int* __restrict__ cursor,
                               int* __restrict__ list, float* __restrict__ wgt) {
    int t = blockIdx.x * blockDim.x + threadIdx.x;
    if (t >= NT) return;
#pragma unroll
    for (int k = 0; k < TOPK; k++) {
        int e = tki[t * 2 + k];
        int pos = atomicAdd(&cursor[e], 1);
        list[off[e] + pos] = t;
        wgt[off[e] + pos] = tkv[t * 2 + k];
    }
    list[off[NE] + t] = t;
    wgt[off[NE] + t] = 1.0f;
}

// ---------------- convert x -> bf16 with k-frag perm within 64-blocks -------
// perm: k = h*32+s*16+q*4+r  ->  c = h*32+q*8+s*4+r
__global__ void convx_kernel(const float* __restrict__ x, u16* __restrict__ xb) {
    int c = blockIdx.x * 256 + threadIdx.x;       // chunk of 8 bf16
    int t = c >> 8;                                // 256 chunks per token
    int cc = c & 255;
    int b64 = cc >> 3, j = cc & 7;
    int h = j >> 2, q = j & 3;
    size_t base = (size_t)t * HD + b64 * 64 + h * 32 + q * 4;
    float4 v0 = *(const float4*)(x + base);
    float4 v1 = *(const float4*)(x + base + 16);
    ushort4 o0, o1;
    o0.x = f2bf(v0.x); o0.y = f2bf(v0.y); o0.z = f2bf(v0.z); o0.w = f2bf(v0.w);
    o1.x = f2bf(v1.x); o1.y = f2bf(v1.y); o1.z = f2bf(v1.z); o1.w = f2bf(v1.w);
    uint4 o;
    o.x = (u32)o0.x | ((u32)o0.y << 16); o.y = (u32)o0.z | ((u32)o0.w << 16);
    o.z = (u32)o1.x | ((u32)o1.y << 16); o.w = (u32)o1.z | ((u32)o1.w << 16);
    *(uint4*)(xb + (size_t)t * HD + b64 * 64 + j * 8) = o;
}

// ---------------- transpose+convert weights: [K][N] f32 -> [N][K'] bf16 -----
__global__ void transw_kernel(const float* __restrict__ src, u16* __restrict__ dst,
                              int K, int N) {
    int e = blockIdx.z;
    src += (size_t)e * K * N;
    dst += (size_t)e * N * K;
    int k0 = blockIdx.y * 64, n0 = blockIdx.x * 64;
    __shared__ u16 Lt[64][68];    // [n][k], padded
    int tid = threadIdx.x;
#pragma unroll
    for (int i = 0; i < 4; i++) {
        int idx = i * 256 + tid;
        int kl = idx >> 4, nq = (idx & 15) * 4;
        float4 v = *(const float4*)(src + (size_t)(k0 + kl) * N + n0 + nq);
        Lt[nq + 0][kl] = f2bf(v.x); Lt[nq + 1][kl] = f2bf(v.y);
        Lt[nq + 2][kl] = f2bf(v.z); Lt[nq + 3][kl] = f2bf(v.w);
    }
    __syncthreads();
#pragma unroll
    for (int c2 = 0; c2 < 2; c2++) {
        int cid = tid * 2 + c2;
        int nr = cid >> 3, j = cid & 7;
        int h = j >> 2, q = j & 3;
        int kb = h * 32 + q * 4;
        uint2 lo = *(const uint2*)&Lt[nr][kb];
        uint2 hi = *(const uint2*)&Lt[nr][kb + 16];
        uint4 o; o.x = lo.x; o.y = lo.y; o.z = hi.x; o.w = hi.y;
        *(uint4*)(dst + (size_t)(n0 + nr) * K + k0 + j * 8) = o;
    }
}

// ---------------- fc1: h1 = SiLU(xb_gathered @ Wt1_g^T), perm'd bf16 out ----
// Double-buffered with COUNTED vmcnt: raw s_barrier (no drain) + explicit
// s_waitcnt vmcnt(8) so the next tile's 8 gl_lds stay in flight under compute.
// LDS XOR-swizzle as round 3 (pre-swizzled global source chunk).
__global__ __launch_bounds__(256) void fc1_kernel(
    const u16* __restrict__ xb, const u16* __restrict__ Wt1,
    const int* __restrict__ off, const int* __restrict__ tileoff,
    const int* __restrict__ list, u16* __restrict__ h1) {
    __shared__ u16 S[4 * 8192];   // As0|Bs0|As1|Bs1 (16KB each), 64KB total
    // XCD-chunked swizzle (nwg = 11*104 = 1144, divisible by 8)
    int nwg = gridDim.x * gridDim.y;
    int orig = blockIdx.y * gridDim.x + blockIdx.x;
    int wg = (orig & 7) * (nwg >> 3) + (orig >> 3);
    int bx = wg % gridDim.x, mt = wg / gridDim.x;

    int g = -1, gto = 0;
#pragma unroll
    for (int gg = 0; gg < NG; gg++)
        if (mt >= tileoff[gg] && mt < tileoff[gg + 1]) { g = gg; gto = tileoff[gg]; }
    if (g < 0) return;
    int goff = off[g], cnt = off[g + 1] - goff;
    int row0 = (mt - gto) * BM;
    const u16* Wb = Wt1 + (size_t)g * (ID * HD);
    int n0 = bx * BN;
    int tid = threadIdx.x, lane = tid & 63, w = tid >> 6;
    int lm = lane >> 3;                              // row within 8-row group
    int lc = (((lane & 7) ^ lm) << 3);               // swizzled source chunk
    const u16* pa[4]; const u16* pb[4];
#pragma unroll
    for (int i = 0; i < 4; i++) {
        int c = i * 4 + w;
        int r = row0 + c * 8 + lm;
        r = (r < cnt) ? r : (cnt - 1);
        pa[i] = xb + (size_t)list[goff + r] * HD + lc;
        pb[i] = Wb + (size_t)(n0 + c * 8 + lm) * HD + lc;
    }
    int wr = w >> 1, wc = w & 1;
    int lr = lane & 15, l7 = lane & 7, q2 = lane >> 4;
    f32x4 acc[4][4] = {};

    auto stage = [&](int b) {
        u16* A = S + b * 16384;
        u16* B = A + 8192;
#pragma unroll
        for (int i = 0; i < 4; i++) {
            gl_lds16(pa[i], A + (i * 4 + w) * 512);
            gl_lds16(pb[i], B + (i * 4 + w) * 512);
            pa[i] += BK; pb[i] += BK;
        }
    };
    auto compute = [&](int b) {
        const u16* A = S + b * 16384;
        const u16* B = A + 8192;
#pragma unroll
        for (int kc = 0; kc < 8; kc += 4) {
            int slot = ((kc + q2) ^ l7) << 3;
            bf16x8 a[4], bb[4];
#pragma unroll
            for (int f = 0; f < 4; f++) {
                a[f]  = __builtin_bit_cast(bf16x8, *(const uint4*)&A[(wr * 64 + f * 16 + lr) * BK + slot]);
                bb[f] = __builtin_bit_cast(bf16x8, *(const uint4*)&B[(wc * 64 + f * 16 + lr) * BK + slot]);
            }
            __builtin_amdgcn_s_setprio(1);
#pragma unroll
            for (int mf = 0; mf < 4; mf++)
#pragma unroll
                for (int nf = 0; nf < 4; nf++)
                    acc[mf][nf] = __builtin_amdgcn_mfma_f32_16x16x32_bf16(a[mf], bb[nf], acc[mf][nf], 0, 0, 0);
            __builtin_amdgcn_s_setprio(0);
        }
    };

    stage(0);
    int cur = 0;
    for (int t = 1; t < HD / BK; ++t) {   // 32 K-steps total
        stage(cur ^ 1);                   // 8 more in flight (<=16 outstanding)
        asm volatile("s_waitcnt vmcnt(8)" ::: "memory");  // oldest 8 (tile t-1) landed
        __builtin_amdgcn_s_barrier();     // all waves' tile t-1 landed; no drain
        compute(cur);
        __builtin_amdgcn_s_barrier();     // all reads of buf cur done before overwrite
        cur ^= 1;
    }
    asm volatile("s_waitcnt vmcnt(0)" ::: "memory");
    __builtin_amdgcn_s_barrier();
    compute(cur);

    // epilogue: SiLU, store h1 with k-frag perm within each 64-col block
    int q4 = q2 * 4;
    int cl = ((lr >> 2) << 3) + (lr & 3);
#pragma unroll
    for (int mf = 0; mf < 4; mf++)
#pragma unroll
        for (int reg = 0; reg < 4; reg++) {
            int r = row0 + wr * 64 + mf * 16 + q4 + reg;
            if (r < cnt) {
                size_t rb = (size_t)(goff + r) * ID + n0 + wc * 64;
#pragma unroll
                for (int nf = 0; nf < 4; nf++) {
                    float v = acc[mf][nf][reg];
                    h1[rb + ((nf >> 1) << 5) + ((nf & 1) << 2) + cl] = f2bf(v / (1.f + __expf(-v)));
                }
            }
        }
}

// ---------------- fc2: y[token] += wgt * (h1 @ Wt2_g^T) ---------------------
__global__ __launch_bounds__(256) void fc2_kernel(
    const u16* __restrict__ h1, const u16* __restrict__ Wt2,
    const int* __restrict__ off, const int* __restrict__ tileoff,
    const int* __restrict__ list, const float* __restrict__ wgt,
    float* __restrict__ y) {
    __shared__ u16 S[4 * 8192];
    // XCD-chunked swizzle (nwg = 16*104 = 1664, divisible by 8)
    int nwg = gridDim.x * gridDim.y;
    int orig = blockIdx.y * gridDim.x + blockIdx.x;
    int wg = (orig & 7) * (nwg >> 3) + (orig >> 3);
    int bx = wg % gridDim.x, mt = wg / gridDim.x;

    int g = -1, gto = 0;
#pragma unroll
    for (int gg = 0; gg < NG; gg++)
        if (mt >= tileoff[gg] && mt < tileoff[gg + 1]) { g = gg; gto = tileoff[gg]; }
    if (g < 0) return;
    int goff = off[g], cnt = off[g + 1] - goff;
    int row0 = (mt - gto) * BM;
    const u16* Wb = Wt2 + (size_t)g * (ID * HD);
    int n0 = bx * BN;
    int tid = threadIdx.x, lane = tid & 63, w = tid >> 6;
    int lm = lane >> 3;
    int lc = (((lane & 7) ^ lm) << 3);
    const u16* pa[4]; const u16* pb[4];
#pragma unroll
    for (int i = 0; i < 4; i++) {
        int c = i * 4 + w;
        int r = row0 + c * 8 + lm;
        r = (r < cnt) ? r : (cnt - 1);
        pa[i] = h1 + (size_t)(goff + r) * ID + lc;           // slot-indexed, perm'd
        pb[i] = Wb + (size_t)(n0 + c * 8 + lm) * ID + lc;    // perm'd weights
    }
    int wr = w >> 1, wc = w & 1;
    int lr = lane & 15, l7 = lane & 7, q2 = lane >> 4;
    f32x4 acc[4][4] = {};

    auto stage = [&](int b) {
        u16* A = S + b * 16384;
        u16* B = A + 8192;
#pragma unroll
        for (int i = 0; i < 4; i++) {
            gl_lds16(pa[i], A + (i * 4 + w) * 512);
            gl_lds16(pb[i], B + (i * 4 + w) * 512);
            pa[i] += BK; pb[i] += BK;
        }
    };
    auto compute = [&](int b) {
        const u16* A = S + b * 16384;
        const u16* B = A + 8192;
#pragma unroll
        for (int kc = 0; kc < 8; kc += 4) {
            int slot = ((kc + q2) ^ l7) << 3;
            bf16x8 a[4], bb[4];
#pragma unroll
            for (int f = 0; f < 4; f++) {
                a[f]  = __builtin_bit_cast(bf16x8, *(const uint4*)&A[(wr * 64 + f * 16 + lr) * BK + slot]);
                bb[f] = __builtin_bit_cast(bf16x8, *(const uint4*)&B[(wc * 64 + f * 16 + lr) * BK + slot]);
            }
            __builtin_amdgcn_s_setprio(1);
#pragma unroll
            for (int mf = 0; mf < 4; mf++)
#pragma unroll
                for (int nf = 0; nf < 4; nf++)
                    acc[mf][nf] = __builtin_amdgcn_mfma_f32_16x16x32_bf16(a[mf], bb[nf], acc[mf][nf], 0, 0, 0);
            __builtin_amdgcn_s_setprio(0);
        }
    };

    stage(0);
    int cur = 0;
    for (int t = 1; t < ID / BK; ++t) {   // 22 K-steps total
        stage(cur ^ 1);
        asm volatile("s_waitcnt vmcnt(8)" ::: "memory");
        __builtin_amdgcn_s_barrier();
        compute(cur);
        __builtin_amdgcn_s_barrier();
        cur ^= 1;
    }
    asm volatile("s_waitcnt vmcnt(0)" ::: "memory");
    __builtin_amdgcn_s_barrier();
    compute(cur);

    int q4 = q2 * 4;
#pragma unroll
    for (int mf = 0; mf < 4; mf++)
#pragma unroll
        for (int reg = 0; reg < 4; reg++) {
            int r = row0 + wr * 64 + mf * 16 + q4 + reg;
            if (r < cnt) {
                int slot = goff + r;
                int tok = list[slot];
                float wv = wgt[slot];
                float* yr = y + (size_t)tok * HD + n0 + wc * 64;
#pragma unroll
                for (int nf = 0; nf < 4; nf++)
                    atomicAdd(yr + nf * 16 + lr, acc[mf][nf][reg] * wv);
            }
        }
}

// ---------------- launch -----------------------------------------------------
extern "C" void kernel_launch(void* const* d_in, const int* in_sizes, int n_in,
                              void* d_out, int out_size, void* d_ws, size_t ws_size,
                              hipStream_t stream) {
    const float* x   = (const float*)d_in[0];
    const float* gw  = (const float*)d_in[1];
    const float* W1  = (const float*)d_in[2];
    const float* W2  = (const float*)d_in[3];
    const float* Ws1 = (const float*)d_in[4];
    const float* Ws2 = (const float*)d_in[5];
    float* out = (float*)d_out;

    char* ws = (char*)d_ws;
    int*   counts  = (int*)(ws + 0);
    int*   cursor  = (int*)(ws + 64);
    int*   off     = (int*)(ws + 128);
    int*   tileoff = (int*)(ws + 192);
    float* imp     = (float*)(ws + 256);
    int*   tki     = (int*)(ws + 320);                    // 32768 B
    float* tkv     = (float*)(ws + 33088);                // 32768 B
    int*   list    = (int*)(ws + 65856);                  // 49152 B
    float* wgt     = (float*)(ws + 115008);               // 49152 B
    // big regions (bytes):
    //   xb  @ 164352 : 16,777,216
    //   Wt1 @ 16,941,568 : 51,904,512   (9 x 1408 x 2048 bf16)
    //   h1  @ 68,846,080 : 34,603,008   (12288 x 1408 bf16, perm'd cols)
    //   Wt2 @ 164352 (aliases xb+Wt1 after fc1) : 51,904,512
    u16* xb  = (u16*)(ws + 164352);
    u16* wt1 = (u16*)(ws + 16941568ULL);
    u16* h1  = (u16*)(ws + 68846080ULL);
    u16* wt2 = (u16*)(ws + 164352);

    hipMemsetAsync(d_out, 0, (size_t)out_size * sizeof(float), stream);
    hipMemsetAsync(d_ws, 0, 320, stream);

    router_kernel<<<NT / 4, 256, 0, stream>>>(x, gw, counts, imp, tki, tkv);
    prep_kernel<<<1, 64, 0, stream>>>(counts, imp, off, tileoff, out + (size_t)NT * HD);
    scatter_kernel<<<NT / 256, 256, 0, stream>>>(tki, tkv, off, cursor, list, wgt);

    convx_kernel<<<NT * HD / 8 / 256, 256, 0, stream>>>(x, xb);
    transw_kernel<<<dim3(ID / 64, HD / 64, NE), 256, 0, stream>>>(W1, wt1, HD, ID);
    transw_kernel<<<dim3(ID / 64, HD / 64, 1), 256, 0, stream>>>(Ws1, wt1 + (size_t)NE * ID * HD, HD, ID);

    fc1_kernel<<<dim3(ID / BN, MT_MAX), 256, 0, stream>>>(xb, wt1, off, tileoff, list, h1);

    // Wt2 overwrites xb/Wt1 (both dead after fc1); stream order guarantees safety
    transw_kernel<<<dim3(HD / 64, ID / 64, NE), 256, 0, stream>>>(W2, wt2, ID, HD);
    transw_kernel<<<dim3(HD / 64, ID / 64, 1), 256, 0, stream>>>(Ws2, wt2 + (size_t)NE * ID * HD, ID, HD);

    fc2_kernel<<<dim3(HD / BN, MT_MAX), 256, 0, stream>>>(h1, wt2, off, tileoff, list, wgt, out);
}

// Round 6
// 347.459 us; speedup vs baseline: 2.4710x; 1.1120x over previous
//
#include <hip/hip_runtime.h>
#include <hip/hip_bf16.h>

#define NT 4096          // B*T tokens
#define HD 2048          // hidden
#define NE 8             // experts
#define TOPK 2
#define ID 1408          // intermediate
#define NG 9             // 8 experts + shared
#define NPAIR (NT*TOPK + NT)   // 12288 rows total
#define BM 128
#define BN 64
#define BK 64
#define MT_MAX 104       // max sum of ceil(cnt/128) over groups (<=72) + 32 shared

typedef unsigned short u16;
typedef unsigned int u32;
typedef unsigned long long u64;
typedef __attribute__((ext_vector_type(8))) short bf16x8;
typedef __attribute__((ext_vector_type(4))) float f32x4;

__device__ __forceinline__ u16 f2bf(float f) {
    u32 u = __builtin_bit_cast(u32, f);
    u += 0x7FFFu + ((u >> 16) & 1u);   // round-to-nearest-even
    return (u16)(u >> 16);
}
__device__ __forceinline__ float bflo(u32 v) { return __builtin_bit_cast(float, v << 16); }
__device__ __forceinline__ float bfhi(u32 v) { return __builtin_bit_cast(float, v & 0xffff0000u); }

// async global->LDS, 16B per lane; lds base must be wave-uniform
typedef __attribute__((address_space(1))) const void gas_void;
typedef __attribute__((address_space(3))) void las_void;
__device__ __forceinline__ void gl_lds16(const void* g, void* l) {
    __builtin_amdgcn_global_load_lds((gas_void*)(u64)g, (las_void*)(u32)(u64)l, 16, 0, 0);
}

// ---------------- router ----------------------------------------------------
__global__ void router_kernel(const float* __restrict__ x, const float* __restrict__ gw,
                              int* __restrict__ counts, float* __restrict__ imp,
                              int* __restrict__ tki, float* __restrict__ tkv) {
    __shared__ float s_imp[NE];
    __shared__ int s_cnt[NE];
    if (threadIdx.x < NE) { s_imp[threadIdx.x] = 0.f; s_cnt[threadIdx.x] = 0; }
    int w = threadIdx.x >> 6, lane = threadIdx.x & 63;
    int t = blockIdx.x * 4 + w;
    float acc[NE];
#pragma unroll
    for (int e = 0; e < NE; e++) acc[e] = 0.f;
    const float* xr = x + (size_t)t * HD;
    for (int i = 0; i < HD / 64; i++) {
        float xv = xr[lane + 64 * i];
#pragma unroll
        for (int e = 0; e < NE; e++) acc[e] += xv * gw[e * HD + lane + 64 * i];
    }
#pragma unroll
    for (int e = 0; e < NE; e++) {
#pragma unroll
        for (int o = 32; o >= 1; o >>= 1) acc[e] += __shfl_xor(acc[e], o, 64);
    }
    __syncthreads();
    if (lane == 0) {
        float mx = acc[0];
        for (int e = 1; e < NE; e++) mx = fmaxf(mx, acc[e]);
        float p[NE], sum = 0.f;
        for (int e = 0; e < NE; e++) { p[e] = expf(acc[e] - mx); sum += p[e]; }
        float inv = 1.f / sum;
        for (int e = 0; e < NE; e++) p[e] *= inv;
        int i1 = 0;
        for (int e = 1; e < NE; e++) if (p[e] > p[i1]) i1 = e;
        int i2 = (i1 == 0) ? 1 : 0;
        for (int e = 0; e < NE; e++) if (e != i1 && p[e] > p[i2]) i2 = e;
        tki[t * 2 + 0] = i1; tkv[t * 2 + 0] = p[i1];
        tki[t * 2 + 1] = i2; tkv[t * 2 + 1] = p[i2];
        for (int e = 0; e < NE; e++) atomicAdd(&s_imp[e], p[e]);
        atomicAdd(&s_cnt[i1], 1); atomicAdd(&s_cnt[i2], 1);
    }
    __syncthreads();
    if (threadIdx.x < NE) {
        atomicAdd(&imp[threadIdx.x], s_imp[threadIdx.x]);
        atomicAdd(&counts[threadIdx.x], s_cnt[threadIdx.x]);
    }
}

// ---------------- prep -------------------------------------------------------
__global__ void prep_kernel(const int* __restrict__ counts, const float* __restrict__ imp,
                            int* __restrict__ off, int* __restrict__ tileoff,
                            float* __restrict__ out_aux) {
    if (threadIdx.x == 0 && blockIdx.x == 0) {
        int o = 0, to = 0;
        for (int g = 0; g < NG; g++) {
            int c = (g < NE) ? counts[g] : NT;
            off[g] = o; tileoff[g] = to;
            o += c; to += (c + BM - 1) / BM;
        }
        off[NG] = o; tileoff[NG] = to;
        float aux = 0.f;
        for (int e = 0; e < NE; e++)
            aux += (imp[e] / (float)NT) * ((float)counts[e] / (float)(NT * TOPK));
        *out_aux = aux * (float)NE;
    }
}

// ---------------- scatter: token lists + slot map (overwrites tki) ----------
__global__ void scatter_kernel(int* __restrict__ tki, const float* __restrict__ tkv,
                               const int* __restrict__ off, int* __restrict__ cursor,
                               int* __restrict__ list, float* __restrict__ wgt) {
    int t = blockIdx.x * blockDim.x + threadIdx.x;
    if (t >= NT) return;
#pragma unroll
    for (int k = 0; k < TOPK; k++) {
        int e = tki[t * 2 + k];                 // read expert id
        int pos = atomicAdd(&cursor[e], 1);
        int s = off[e] + pos;
        list[s] = t;
        wgt[s] = tkv[t * 2 + k];
        tki[t * 2 + k] = s;                     // overwrite with slot map
    }
    list[off[NE] + t] = t;
    wgt[off[NE] + t] = 1.0f;
}

// ---------------- convert x -> bf16 with k-frag perm within 64-blocks -------
__global__ void convx_kernel(const float* __restrict__ x, u16* __restrict__ xb) {
    int c = blockIdx.x * 256 + threadIdx.x;
    int t = c >> 8;
    int cc = c & 255;
    int b64 = cc >> 3, j = cc & 7;
    int h = j >> 2, q = j & 3;
    size_t base = (size_t)t * HD + b64 * 64 + h * 32 + q * 4;
    float4 v0 = *(const float4*)(x + base);
    float4 v1 = *(const float4*)(x + base + 16);
    ushort4 o0, o1;
    o0.x = f2bf(v0.x); o0.y = f2bf(v0.y); o0.z = f2bf(v0.z); o0.w = f2bf(v0.w);
    o1.x = f2bf(v1.x); o1.y = f2bf(v1.y); o1.z = f2bf(v1.z); o1.w = f2bf(v1.w);
    uint4 o;
    o.x = (u32)o0.x | ((u32)o0.y << 16); o.y = (u32)o0.z | ((u32)o0.w << 16);
    o.z = (u32)o1.x | ((u32)o1.y << 16); o.w = (u32)o1.z | ((u32)o1.w << 16);
    *(uint4*)(xb + (size_t)t * HD + b64 * 64 + j * 8) = o;
}

// ---------------- transpose+convert weights (experts + shared in one grid) --
__global__ void transw_kernel(const float* __restrict__ W, const float* __restrict__ Wsh,
                              u16* __restrict__ dst, int K, int N) {
    int e = blockIdx.z;
    const float* src = (e < NE) ? (W + (size_t)e * K * N) : Wsh;
    dst += (size_t)e * N * K;
    int k0 = blockIdx.y * 64, n0 = blockIdx.x * 64;
    __shared__ u16 Lt[64][68];
    int tid = threadIdx.x;
#pragma unroll
    for (int i = 0; i < 4; i++) {
        int idx = i * 256 + tid;
        int kl = idx >> 4, nq = (idx & 15) * 4;
        float4 v = *(const float4*)(src + (size_t)(k0 + kl) * N + n0 + nq);
        Lt[nq + 0][kl] = f2bf(v.x); Lt[nq + 1][kl] = f2bf(v.y);
        Lt[nq + 2][kl] = f2bf(v.z); Lt[nq + 3][kl] = f2bf(v.w);
    }
    __syncthreads();
#pragma unroll
    for (int c2 = 0; c2 < 2; c2++) {
        int cid = tid * 2 + c2;
        int nr = cid >> 3, j = cid & 7;
        int h = j >> 2, q = j & 3;
        int kb = h * 32 + q * 4;
        uint2 lo = *(const uint2*)&Lt[nr][kb];
        uint2 hi = *(const uint2*)&Lt[nr][kb + 16];
        uint4 o; o.x = lo.x; o.y = lo.y; o.z = hi.x; o.w = hi.y;
        *(uint4*)(dst + (size_t)(n0 + nr) * K + k0 + j * 8) = o;
    }
}

// ---------------- fc1: h1 = SiLU(xb_gathered @ Wt1_g^T), perm'd bf16 out ----
// 128x64 tile, dbuf BK=64, counted vmcnt(6), LDS XOR-swizzle (round-3 scheme).
__global__ __launch_bounds__(256) void fc1_kernel(
    const u16* __restrict__ xb, const u16* __restrict__ Wt1,
    const int* __restrict__ off, const int* __restrict__ tileoff,
    const int* __restrict__ list, u16* __restrict__ h1) {
    __shared__ u16 S[2 * 12288];   // per buffer: A 128x64 (16KB) + B 64x64 (8KB)
    int nwg = gridDim.x * gridDim.y;           // 22*104 = 2288, %8==0
    int orig = blockIdx.y * gridDim.x + blockIdx.x;
    int wg = (orig & 7) * (nwg >> 3) + (orig >> 3);
    int bx = wg % gridDim.x, mt = wg / gridDim.x;

    int g = -1, gto = 0;
#pragma unroll
    for (int gg = 0; gg < NG; gg++)
        if (mt >= tileoff[gg] && mt < tileoff[gg + 1]) { g = gg; gto = tileoff[gg]; }
    if (g < 0) return;
    int goff = off[g], cnt = off[g + 1] - goff;
    int row0 = (mt - gto) * BM;
    const u16* Wb = Wt1 + (size_t)g * (ID * HD);
    int n0 = bx * BN;
    int tid = threadIdx.x, lane = tid & 63, w = tid >> 6;
    int lm = lane >> 3;
    int lc = (((lane & 7) ^ lm) << 3);          // swizzled source chunk
    const u16* pa[4]; const u16* pb[2];
#pragma unroll
    for (int i = 0; i < 4; i++) {
        int c = i * 4 + w;
        int r = row0 + c * 8 + lm;
        r = (r < cnt) ? r : (cnt - 1);
        pa[i] = xb + (size_t)list[goff + r] * HD + lc;
    }
#pragma unroll
    for (int i = 0; i < 2; i++) {
        int c = i * 4 + w;
        pb[i] = Wb + (size_t)(n0 + c * 8 + lm) * HD + lc;
    }
    int wr = w >> 1, wc = w & 1;
    int lr = lane & 15, l7 = lane & 7, q2 = lane >> 4;
    f32x4 acc[4][2] = {};

    auto stage = [&](int b) {
        u16* A = S + b * 12288;
        u16* B = A + 8192;
#pragma unroll
        for (int i = 0; i < 4; i++) { gl_lds16(pa[i], A + (i * 4 + w) * 512); pa[i] += BK; }
#pragma unroll
        for (int i = 0; i < 2; i++) { gl_lds16(pb[i], B + (i * 4 + w) * 512); pb[i] += BK; }
    };
    auto compute = [&](int b) {
        const u16* A = S + b * 12288;
        const u16* B = A + 8192;
#pragma unroll
        for (int kc = 0; kc < 8; kc += 4) {
            int slot = ((kc + q2) ^ l7) << 3;
            bf16x8 a[4], bb[2];
#pragma unroll
            for (int f = 0; f < 4; f++)
                a[f] = __builtin_bit_cast(bf16x8, *(const uint4*)&A[(wr * 64 + f * 16 + lr) * BK + slot]);
#pragma unroll
            for (int f = 0; f < 2; f++)
                bb[f] = __builtin_bit_cast(bf16x8, *(const uint4*)&B[(wc * 32 + f * 16 + lr) * BK + slot]);
            __builtin_amdgcn_s_setprio(1);
#pragma unroll
            for (int mf = 0; mf < 4; mf++)
#pragma unroll
                for (int nf = 0; nf < 2; nf++)
                    acc[mf][nf] = __builtin_amdgcn_mfma_f32_16x16x32_bf16(a[mf], bb[nf], acc[mf][nf], 0, 0, 0);
            __builtin_amdgcn_s_setprio(0);
        }
    };

    stage(0);
    int cur = 0;
    for (int t = 1; t < HD / BK; ++t) {
        stage(cur ^ 1);
        asm volatile("s_waitcnt vmcnt(6)" ::: "memory");
        __builtin_amdgcn_s_barrier();
        compute(cur);
        __builtin_amdgcn_s_barrier();
        cur ^= 1;
    }
    asm volatile("s_waitcnt vmcnt(0)" ::: "memory");
    __builtin_amdgcn_s_barrier();
    compute(cur);

    int q4 = q2 * 4;
    int cl = ((lr >> 2) << 3) + (lr & 3);
#pragma unroll
    for (int mf = 0; mf < 4; mf++)
#pragma unroll
        for (int reg = 0; reg < 4; reg++) {
            int r = row0 + wr * 64 + mf * 16 + q4 + reg;
            if (r < cnt) {
                size_t rb = (size_t)(goff + r) * ID + n0;
#pragma unroll
                for (int nf = 0; nf < 2; nf++) {
                    float v = acc[mf][nf][reg];
                    h1[rb + wc * 32 + (nf << 2) + cl] = f2bf(v / (1.f + __expf(-v)));
                }
            }
        }
}

// ---------------- fc2: EO=1 -> eo[slot] bf16 stores; EO=0 -> atomic y -------
template <bool EO>
__global__ __launch_bounds__(256) void fc2_kernel(
    const u16* __restrict__ h1, const u16* __restrict__ Wt2,
    const int* __restrict__ off, const int* __restrict__ tileoff,
    const int* __restrict__ list, const float* __restrict__ wgt,
    u16* __restrict__ eo, float* __restrict__ y) {
    __shared__ u16 S[2 * 12288];
    int nwg = gridDim.x * gridDim.y;            // 32*104 = 3328, %8==0
    int orig = blockIdx.y * gridDim.x + blockIdx.x;
    int wg = (orig & 7) * (nwg >> 3) + (orig >> 3);
    int bx = wg % gridDim.x, mt = wg / gridDim.x;

    int g = -1, gto = 0;
#pragma unroll
    for (int gg = 0; gg < NG; gg++)
        if (mt >= tileoff[gg] && mt < tileoff[gg + 1]) { g = gg; gto = tileoff[gg]; }
    if (g < 0) return;
    int goff = off[g], cnt = off[g + 1] - goff;
    int row0 = (mt - gto) * BM;
    const u16* Wb = Wt2 + (size_t)g * (ID * HD);
    int n0 = bx * BN;
    int tid = threadIdx.x, lane = tid & 63, w = tid >> 6;
    int lm = lane >> 3;
    int lc = (((lane & 7) ^ lm) << 3);
    const u16* pa[4]; const u16* pb[2];
#pragma unroll
    for (int i = 0; i < 4; i++) {
        int c = i * 4 + w;
        int r = row0 + c * 8 + lm;
        r = (r < cnt) ? r : (cnt - 1);
        pa[i] = h1 + (size_t)(goff + r) * ID + lc;           // slot-indexed, perm'd
    }
#pragma unroll
    for (int i = 0; i < 2; i++) {
        int c = i * 4 + w;
        pb[i] = Wb + (size_t)(n0 + c * 8 + lm) * ID + lc;    // perm'd weights
    }
    int wr = w >> 1, wc = w & 1;
    int lr = lane & 15, l7 = lane & 7, q2 = lane >> 4;
    f32x4 acc[4][2] = {};

    auto stage = [&](int b) {
        u16* A = S + b * 12288;
        u16* B = A + 8192;
#pragma unroll
        for (int i = 0; i < 4; i++) { gl_lds16(pa[i], A + (i * 4 + w) * 512); pa[i] += BK; }
#pragma unroll
        for (int i = 0; i < 2; i++) { gl_lds16(pb[i], B + (i * 4 + w) * 512); pb[i] += BK; }
    };
    auto compute = [&](int b) {
        const u16* A = S + b * 12288;
        const u16* B = A + 8192;
#pragma unroll
        for (int kc = 0; kc < 8; kc += 4) {
            int slot = ((kc + q2) ^ l7) << 3;
            bf16x8 a[4], bb[2];
#pragma unroll
            for (int f = 0; f < 4; f++)
                a[f] = __builtin_bit_cast(bf16x8, *(const uint4*)&A[(wr * 64 + f * 16 + lr) * BK + slot]);
#pragma unroll
            for (int f = 0; f < 2; f++)
                bb[f] = __builtin_bit_cast(bf16x8, *(const uint4*)&B[(wc * 32 + f * 16 + lr) * BK + slot]);
            __builtin_amdgcn_s_setprio(1);
#pragma unroll
            for (int mf = 0; mf < 4; mf++)
#pragma unroll
                for (int nf = 0; nf < 2; nf++)
                    acc[mf][nf] = __builtin_amdgcn_mfma_f32_16x16x32_bf16(a[mf], bb[nf], acc[mf][nf], 0, 0, 0);
            __builtin_amdgcn_s_setprio(0);
        }
    };

    stage(0);
    int cur = 0;
    for (int t = 1; t < ID / BK; ++t) {
        stage(cur ^ 1);
        asm volatile("s_waitcnt vmcnt(6)" ::: "memory");
        __builtin_amdgcn_s_barrier();
        compute(cur);
        __builtin_amdgcn_s_barrier();
        cur ^= 1;
    }
    asm volatile("s_waitcnt vmcnt(0)" ::: "memory");
    __builtin_amdgcn_s_barrier();
    compute(cur);

    int q4 = q2 * 4;
#pragma unroll
    for (int mf = 0; mf < 4; mf++)
#pragma unroll
        for (int reg = 0; reg < 4; reg++) {
            int r = row0 + wr * 64 + mf * 16 + q4 + reg;
            if (r < cnt) {
                int slot = goff + r;
                if (EO) {
                    size_t rb = (size_t)slot * HD + n0 + wc * 32;
#pragma unroll
                    for (int nf = 0; nf < 2; nf++)
                        eo[rb + nf * 16 + lr] = f2bf(acc[mf][nf][reg]);
                } else {
                    int tok = list[slot];
                    float wv = wgt[slot];
                    float* yr = y + (size_t)tok * HD + n0 + wc * 32;
#pragma unroll
                    for (int nf = 0; nf < 2; nf++)
                        atomicAdd(yr + nf * 16 + lr, acc[mf][nf][reg] * wv);
                }
            }
        }
}

// ---------------- combine: y[t] = w0*eo[s0] + w1*eo[s1] + eo[shared] --------
__global__ __launch_bounds__(256) void combine_kernel(
    const u16* __restrict__ eo, const int* __restrict__ smap,
    const float* __restrict__ tkv, const int* __restrict__ off,
    float* __restrict__ y) {
    int idx = blockIdx.x * 256 + threadIdx.x;
    int t = idx >> 8;
    int cc = (idx & 255) << 3;
    int s0 = smap[t * 2 + 0], s1 = smap[t * 2 + 1];
    float w0 = tkv[t * 2 + 0], w1 = tkv[t * 2 + 1];
    int s2 = off[NE] + t;
    uint4 A = *(const uint4*)(eo + (size_t)s0 * HD + cc);
    uint4 B = *(const uint4*)(eo + (size_t)s1 * HD + cc);
    uint4 C = *(const uint4*)(eo + (size_t)s2 * HD + cc);
    float4 o0, o1;
    o0.x = w0 * bflo(A.x) + w1 * bflo(B.x) + bflo(C.x);
    o0.y = w0 * bfhi(A.x) + w1 * bfhi(B.x) + bfhi(C.x);
    o0.z = w0 * bflo(A.y) + w1 * bflo(B.y) + bflo(C.y);
    o0.w = w0 * bfhi(A.y) + w1 * bfhi(B.y) + bfhi(C.y);
    o1.x = w0 * bflo(A.z) + w1 * bflo(B.z) + bflo(C.z);
    o1.y = w0 * bfhi(A.z) + w1 * bfhi(B.z) + bfhi(C.z);
    o1.z = w0 * bflo(A.w) + w1 * bflo(B.w) + bflo(C.w);
    o1.w = w0 * bfhi(A.w) + w1 * bfhi(B.w) + bfhi(C.w);
    float* yr = y + (size_t)t * HD + cc;
    *(float4*)yr = o0;
    *(float4*)(yr + 4) = o1;
}

// ---------------- launch -----------------------------------------------------
extern "C" void kernel_launch(void* const* d_in, const int* in_sizes, int n_in,
                              void* d_out, int out_size, void* d_ws, size_t ws_size,
                              hipStream_t stream) {
    const float* x   = (const float*)d_in[0];
    const float* gw  = (const float*)d_in[1];
    const float* W1  = (const float*)d_in[2];
    const float* W2  = (const float*)d_in[3];
    const float* Ws1 = (const float*)d_in[4];
    const float* Ws2 = (const float*)d_in[5];
    float* out = (float*)d_out;

    char* ws = (char*)d_ws;
    int*   counts  = (int*)(ws + 0);
    int*   cursor  = (int*)(ws + 64);
    int*   off     = (int*)(ws + 128);
    int*   tileoff = (int*)(ws + 192);
    float* imp     = (float*)(ws + 256);
    int*   tki     = (int*)(ws + 320);                    // becomes slot-map after scatter
    float* tkv     = (float*)(ws + 33088);
    int*   list    = (int*)(ws + 65856);
    float* wgt     = (float*)(ws + 115008);
    // big regions (bytes):
    //   xb  @ 164352        : 16,777,216
    //   Wt1 @ 16,941,568    : 51,904,512   (9 x 1408 x 2048 bf16)
    //   h1  @ 68,846,080    : 34,603,008   (12288 x 1408 bf16, perm'd cols)
    //   Wt2 @ 164352 (aliases xb+Wt1 after fc1) : 51,904,512
    //   eo  @ 103,449,088   : 50,331,648   (12288 x 2048 bf16) -- only if ws allows
    u16* xb  = (u16*)(ws + 164352);
    u16* wt1 = (u16*)(ws + 16941568ULL);
    u16* h1  = (u16*)(ws + 68846080ULL);
    u16* wt2 = (u16*)(ws + 164352);
    u16* eo  = (u16*)(ws + 103449088ULL);
    const bool use_eo = (ws_size >= 153780736ULL);

    if (!use_eo)
        hipMemsetAsync(d_out, 0, (size_t)out_size * sizeof(float), stream);
    hipMemsetAsync(d_ws, 0, 320, stream);

    router_kernel<<<NT / 4, 256, 0, stream>>>(x, gw, counts, imp, tki, tkv);
    prep_kernel<<<1, 64, 0, stream>>>(counts, imp, off, tileoff, out + (size_t)NT * HD);
    scatter_kernel<<<NT / 256, 256, 0, stream>>>(tki, tkv, off, cursor, list, wgt);

    convx_kernel<<<NT * HD / 8 / 256, 256, 0, stream>>>(x, xb);
    transw_kernel<<<dim3(ID / 64, HD / 64, NG), 256, 0, stream>>>(W1, Ws1, wt1, HD, ID);

    fc1_kernel<<<dim3(ID / BN, MT_MAX), 256, 0, stream>>>(xb, wt1, off, tileoff, list, h1);

    // Wt2 overwrites xb/Wt1 (both dead after fc1); stream order guarantees safety
    transw_kernel<<<dim3(HD / 64, ID / 64, NG), 256, 0, stream>>>(W2, Ws2, wt2, ID, HD);

    if (use_eo) {
        fc2_kernel<true><<<dim3(HD / BN, MT_MAX), 256, 0, stream>>>(
            h1, wt2, off, tileoff, list, wgt, eo, out);
        combine_kernel<<<NT, 256, 0, stream>>>(eo, tki, tkv, off, out);
    } else {
        fc2_kernel<false><<<dim3(HD / BN, MT_MAX), 256, 0, stream>>>(
            h1, wt2, off, tileoff, list, wgt, eo, out);
    }
}